// Round 1
// baseline (1689.615 us; speedup 1.0000x reference)
//
#include <hip/hip_runtime.h>
#include <math.h>

#define NAg 8000
#define NTr 30000
#define NE  150000

// ---- workspace layout (float offsets) ----
#define XA_OFF 0          // 8000*64
#define XT_OFF 512000     // 30000*64
#define H0_OFF 2432000    // 8000*256
#define H1_OFF 4480000    // 30000*256
#define H2_OFF 12160000   // 8000*256
#define H3_OFF 14208000   // 30000*256
#define ALS0 21888000
#define ALS1 21920000
#define ALS2 22040000
#define ALS3 22072000
#define ALD0 22192000
#define ALD1 22312000
#define ALD2 22344000
#define ALD3 22464000
#define M0 22496000
#define M1 22616000
#define M2 22648000
#define M3 22768000
#define DEN0 22800000
#define DEN1 22920000
#define DEN2 22952000
#define DEN3 23072000
#define OAACC 23104000    // 8000*64
#define OTACC 23616000    // 30000*64
#define BNST 25536000     // [type][2][64]
#define CST  25536256     // [type][3][64] (sum,sumsq,max-mapped)
#define ZOFF 22496000
#define ZLEN 3040256      // floats zeroed per layer (m,den,acc,bnstats)

__device__ __forceinline__ float lrelu(float x){ return x >= 0.f ? x : 0.2f*x; }
__device__ __forceinline__ unsigned fmap(float f){ unsigned u=__float_as_uint(f); return (u&0x80000000u)? ~u : (u|0x80000000u); }
__device__ __forceinline__ float funmap(unsigned u){ return (u&0x80000000u)? __uint_as_float(u&0x7FFFFFFFu) : __uint_as_float(~u); }
__device__ __forceinline__ float softplusf(float x){ return fmaxf(x,0.f) + log1pf(expf(-fabsf(x))); }
__device__ __forceinline__ float wred64(float v){
  #pragma unroll
  for (int o=32;o;o>>=1) v += __shfl_xor(v,o);
  return v;
}
__device__ __forceinline__ float wred32(float v){
  #pragma unroll
  for (int o=16;o;o>>=1) v += __shfl_xor(v,o,32);
  return v;
}
__device__ __forceinline__ int selNd(int r){ return (r&1)? NAg : NTr; }
__device__ __forceinline__ int selH(int r){ return r==0?H0_OFF: r==1?H1_OFF: r==2?H2_OFF:H3_OFF; }
__device__ __forceinline__ int selALS(int r){ return r==0?ALS0: r==1?ALS1: r==2?ALS2:ALS3; }
__device__ __forceinline__ int selALD(int r){ return r==0?ALD0: r==1?ALD1: r==2?ALD2:ALD3; }
__device__ __forceinline__ int selM(int r){ return r==0?M0: r==1?M1: r==2?M2:M3; }
__device__ __forceinline__ int selDEN(int r){ return r==0?DEN0: r==1?DEN1: r==2?DEN2:DEN3; }

// ---------------- encoder: x = relu(X @ W + b) ----------------
__global__ __launch_bounds__(64) void k_encoder(const float* xA, const float* xT,
    const float* aeW, const float* aeB, const float* teW, const float* teB, float* ws) {
  int type = blockIdx.y;
  int n = blockIdx.x;
  int N = type ? NTr : NAg;
  if (n >= N) return;
  int F = type ? 48 : 32;
  const float* X = type ? xT : xA;
  const float* W = type ? teW : aeW;
  const float* B = type ? teB : aeB;
  float* out = ws + (type ? XT_OFF : XA_OFF);
  __shared__ float xs[48];
  int t = threadIdx.x;
  if (t < F) xs[t] = X[n*F + t];
  __syncthreads();
  float acc = B[t];
  for (int k = 0; k < F; ++k) acc += xs[k] * W[k*64 + t];
  out[n*64 + t] = fmaxf(acc, 0.f);
}

// ---------------- al_d[n,h] = x_dst[n,:] . (W @ a_dst[h]) ----------------
__global__ __launch_bounds__(256) void k_ald(const float* convW, const float* convAdst,
                                             float* ws, int layer) {
  int r = blockIdx.y;
  int Nd = selNd(r);
  const float* W  = convW + (size_t)(layer*4 + r)*64*256;
  const float* ad = convAdst + (size_t)(layer*4 + r)*256;
  __shared__ float Wad[64*4];
  int t = threadIdx.x;
  {
    int k = t >> 2, h = t & 3;
    float s = 0.f;
    for (int c = 0; c < 64; ++c) s += W[k*256 + h*64 + c] * ad[h*64 + c];
    Wad[k*4 + h] = s;
  }
  __syncthreads();
  const float* xd = ws + ((r & 1) ? XA_OFF : XT_OFF);  // dst node type
  float* ald = ws + selALD(r);
  int n = blockIdx.x * 64 + (t >> 2);
  if (n >= Nd) return;
  int h = t & 3;
  float s = 0.f;
  for (int k = 0; k < 64; ++k) s += xd[n*64 + k] * Wad[k*4 + h];
  ald[n*4 + h] = s;
}

// ---------------- h = x_src @ W   and   al_s = sum(h * a_src) ----------------
// tile: 16 rows x 256 cols per 256-thread block; thread: 4 rows x 4 cols
__global__ __launch_bounds__(256) void k_h_als(const float* convW, const float* convAsrc,
                                               float* ws, int layer) {
  int r = blockIdx.y;
  int Ns = (r & 1) ? NTr : NAg;
  int row0 = blockIdx.x * 16;
  if (row0 >= Ns) return;
  const float* W  = convW + (size_t)(layer*4 + r)*64*256;
  const float* as = convAsrc + (size_t)(layer*4 + r)*256;
  const float* xg = ws + ((r & 1) ? XT_OFF : XA_OFF);
  float* h  = ws + selH(r);
  float* als = ws + selALS(r);
  __shared__ float xs[16][64];
  __shared__ float asl[256];
  int t = threadIdx.x;
  asl[t] = as[t];
  #pragma unroll
  for (int i = 0; i < 4; ++i) {
    int lin = i*256 + t;
    xs[lin>>6][lin&63] = xg[(row0 + (lin>>6))*64 + (lin&63)];
  }
  __syncthreads();
  int c0 = t & 63;
  int tr = t >> 6;   // wave id == thread-row group; rows tr*4..tr*4+3; cols c0+j*64 (head j)
  float acc[4][4];
  #pragma unroll
  for (int i=0;i<4;i++){ acc[i][0]=0;acc[i][1]=0;acc[i][2]=0;acc[i][3]=0; }
  const float* Wc = W + c0;
  for (int k4 = 0; k4 < 16; ++k4) {
    float4 xv[4];
    #pragma unroll
    for (int i = 0; i < 4; ++i) xv[i] = *(const float4*)&xs[tr*4+i][k4*4];
    #pragma unroll
    for (int kk = 0; kk < 4; ++kk) {
      int k = k4*4 + kk;
      float w0 = Wc[k*256], w1 = Wc[k*256+64], w2 = Wc[k*256+128], w3 = Wc[k*256+192];
      #pragma unroll
      for (int i = 0; i < 4; ++i) {
        float x = (kk==0)?xv[i].x:(kk==1)?xv[i].y:(kk==2)?xv[i].z:xv[i].w;
        acc[i][0] += x*w0; acc[i][1] += x*w1; acc[i][2] += x*w2; acc[i][3] += x*w3;
      }
    }
  }
  #pragma unroll
  for (int i = 0; i < 4; ++i) {
    int row = row0 + tr*4 + i;
    #pragma unroll
    for (int j = 0; j < 4; ++j) h[(size_t)row*256 + j*64 + c0] = acc[i][j];
  }
  // al_s: reduce acc[i][j]*a_src[j, c0] over the 64 lanes of this wave
  #pragma unroll
  for (int i = 0; i < 4; ++i) {
    #pragma unroll
    for (int j = 0; j < 4; ++j) {
      float v = acc[i][j] * asl[j*64 + c0];
      v = wred64(v);
      if (c0 == 0) als[(row0 + tr*4 + i)*4 + j] = v;
    }
  }
}

// ---------------- edge pass A: segment max (mapped-uint atomicMax) ----------------
__global__ __launch_bounds__(256) void k_edgeA(const int* s0,const int* d0_,const int* s1,const int* d1_,
    const int* s2,const int* d2_,const int* s3,const int* d3_, float* ws) {
  int r = blockIdx.y;
  const int* sp = r==0? s0 : r==1? s1 : r==2? s2 : s3;
  const int* dp = r==0? d0_ : r==1? d1_ : r==2? d2_ : d3_;
  int e = blockIdx.x*256 + threadIdx.x;
  if (e >= NE) return;
  int s = sp[e], d = dp[e];
  float4 a4 = *(const float4*)(ws + selALS(r) + (size_t)s*4);
  float4 b4 = *(const float4*)(ws + selALD(r) + (size_t)d*4);
  unsigned* mu = (unsigned*)(ws + selM(r)) + (size_t)d*4;
  atomicMax(&mu[0], fmap(lrelu(a4.x + b4.x)));
  atomicMax(&mu[1], fmap(lrelu(a4.y + b4.y)));
  atomicMax(&mu[2], fmap(lrelu(a4.z + b4.z)));
  atomicMax(&mu[3], fmap(lrelu(a4.w + b4.w)));
}

// ---------------- unmap m (in place), empty segments -> 0 ----------------
__global__ __launch_bounds__(256) void k_unmap(float* ws) {
  int r = blockIdx.y;
  int n4 = selNd(r) * 4;
  int i = blockIdx.x*256 + threadIdx.x;
  if (i >= n4) return;
  unsigned* mu = (unsigned*)(ws + selM(r));
  unsigned u = mu[i];
  ((float*)mu)[i] = (u == 0u) ? 0.f : funmap(u);
}

// ---------------- edge pass B: den = segment_sum(exp(e - m[dst])) ----------------
__global__ __launch_bounds__(256) void k_edgeB(const int* s0,const int* d0_,const int* s1,const int* d1_,
    const int* s2,const int* d2_,const int* s3,const int* d3_, float* ws) {
  int r = blockIdx.y;
  const int* sp = r==0? s0 : r==1? s1 : r==2? s2 : s3;
  const int* dp = r==0? d0_ : r==1? d1_ : r==2? d2_ : d3_;
  int e = blockIdx.x*256 + threadIdx.x;
  if (e >= NE) return;
  int s = sp[e], d = dp[e];
  float4 a4 = *(const float4*)(ws + selALS(r) + (size_t)s*4);
  float4 b4 = *(const float4*)(ws + selALD(r) + (size_t)d*4);
  float4 m4 = *(const float4*)(ws + selM(r) + (size_t)d*4);
  float* den = ws + selDEN(r) + (size_t)d*4;
  atomicAdd(&den[0], expf(lrelu(a4.x + b4.x) - m4.x));
  atomicAdd(&den[1], expf(lrelu(a4.y + b4.y) - m4.y));
  atomicAdd(&den[2], expf(lrelu(a4.z + b4.z) - m4.z));
  atomicAdd(&den[3], expf(lrelu(a4.w + b4.w) - m4.w));
}

// ---------------- edge pass C: out[dst,c] += 0.125 * sum_h alpha_h * h[src,h,c] ----------------
// one wave per edge, one lane per channel
__global__ __launch_bounds__(256) void k_edgeC(const int* s0,const int* d0_,const int* s1,const int* d1_,
    const int* s2,const int* d2_,const int* s3,const int* d3_, float* ws) {
  int r = blockIdx.y;
  const int* sp = r==0? s0 : r==1? s1 : r==2? s2 : s3;
  const int* dp = r==0? d0_ : r==1? d1_ : r==2? d2_ : d3_;
  int wv = threadIdx.x >> 6, lane = threadIdx.x & 63;
  int e = blockIdx.x*4 + wv;
  int s = sp[e], d = dp[e];
  float4 a4 = *(const float4*)(ws + selALS(r) + (size_t)s*4);
  float4 b4 = *(const float4*)(ws + selALD(r) + (size_t)d*4);
  float4 m4 = *(const float4*)(ws + selM(r) + (size_t)d*4);
  float4 dn = *(const float4*)(ws + selDEN(r) + (size_t)d*4);
  float p0 = expf(lrelu(a4.x + b4.x) - m4.x) / (dn.x + 1e-16f);
  float p1 = expf(lrelu(a4.y + b4.y) - m4.y) / (dn.y + 1e-16f);
  float p2 = expf(lrelu(a4.z + b4.z) - m4.z) / (dn.z + 1e-16f);
  float p3 = expf(lrelu(a4.w + b4.w) - m4.w) / (dn.w + 1e-16f);
  const float* hp = ws + selH(r) + (size_t)s*256;
  float v = p0*hp[lane] + p1*hp[64+lane] + p2*hp[128+lane] + p3*hp[192+lane];
  float* accb = ws + ((r & 1) ? OAACC : OTACC);
  atomicAdd(accb + (size_t)d*64 + lane, 0.125f * v);
}

// ---------------- relu(acc + avg bias) in place + per-channel sum/sumsq ----------------
__global__ __launch_bounds__(256) void k_relustats(const float* convBias, float* ws, int layer) {
  int type = blockIdx.y;                       // 0 agent, 1 track
  int N = type ? NTr : NAg;
  float* acc = ws + (type ? OTACC : OAACC);
  int rA = type ? 0 : 1, rB = type ? 2 : 3;
  int t = threadIdx.x;
  int c = t & 63;
  float bavg = 0.5f*(convBias[(layer*4 + rA)*64 + c] + convBias[(layer*4 + rB)*64 + c]);
  float s1 = 0.f, s2 = 0.f;
  for (int n = blockIdx.x*4 + (t>>6); n < N; n += gridDim.x*4) {
    float z = fmaxf(acc[(size_t)n*64 + c] + bavg, 0.f);
    acc[(size_t)n*64 + c] = z;
    s1 += z; s2 += z*z;
  }
  __shared__ float sd[2][256];
  sd[0][t] = s1; sd[1][t] = s2;
  __syncthreads();
  if (t < 64) {
    s1 = sd[0][t] + sd[0][t+64] + sd[0][t+128] + sd[0][t+192];
    s2 = sd[1][t] + sd[1][t+64] + sd[1][t+128] + sd[1][t+192];
    atomicAdd(&ws[BNST + type*128 + c], s1);
    atomicAdd(&ws[BNST + type*128 + 64 + c], s2);
  }
}

// ---------------- batchnorm + residual, writes xa/xt in place ----------------
__global__ __launch_bounds__(256) void k_bnnorm(const float* bnG, const float* bnB, float* ws, int layer) {
  int type = blockIdx.y;
  int N = type ? NTr : NAg;
  float* acc = ws + (type ? OTACC : OAACC);
  float* x = ws + (type ? XT_OFF : XA_OFF);
  int i = blockIdx.x*256 + threadIdx.x;
  if (i >= N*64) return;
  int c = i & 63;
  float Nf = (float)N;
  float s1 = ws[BNST + type*128 + c], s2 = ws[BNST + type*128 + 64 + c];
  float mu = s1/Nf, var = s2/Nf - mu*mu;
  float g = bnG[(layer*2 + type)*64 + c], b = bnB[(layer*2 + type)*64 + c];
  float y = g*(acc[i]-mu)*rsqrtf(var + 1e-5f) + b;
  if (layer > 0) y += x[i];
  x[i] = y;
}

// ---------------- actor heads: per-node two small MLPs with LN ----------------
__global__ __launch_bounds__(256) void k_actor(const float* aW1, const float* ab1, const float* ag,
    const float* abe, const float* aW2, const float* ab2, const float* ws, float* out) {
  int type = blockIdx.y;
  int N = type ? NTr : NAg;
  int grp = threadIdx.x >> 5, j = threadIdx.x & 31;
  int n = blockIdx.x*8 + grp;
  if (n >= N) return;
  const float* x = ws + (type ? XT_OFF : XA_OFF) + (size_t)n*64;
  int iA = type ? 2 : 0;
  float vals[2];
  #pragma unroll
  for (int p = 0; p < 2; ++p) {
    int i = iA + p;
    float tv = ab1[i*32 + j];
    for (int k = 0; k < 64; ++k) tv += x[k] * aW1[i*2048 + k*32 + j];
    float mu = wred32(tv) * (1.f/32.f);
    float dz = tv - mu;
    float var = wred32(dz*dz) * (1.f/32.f);
    float hn = fmaxf(ag[i*32+j]*dz*rsqrtf(var + 1e-5f) + abe[i*32+j], 0.f);
    float s = wred32(hn * aW2[i*32 + j]) + ab2[i];
    vals[p] = softplusf(s) + 1.f;
  }
  if (j == 0) {
    int offA = type ? 24000 : 0, offB = type ? 54000 : 8000, offC = type ? 84000 : 16000;
    out[offA + n] = vals[0];
    out[offB + n] = vals[1];
    out[offC + n] = vals[0] / (vals[0] + vals[1]);
  }
}

// ---------------- critic column stats: sum, sumsq, max ----------------
__global__ __launch_bounds__(256) void k_criticstats(float* ws) {
  int type = blockIdx.y;
  int N = type ? NTr : NAg;
  const float* x = ws + (type ? XT_OFF : XA_OFF);
  int t = threadIdx.x;
  int c = t & 63;
  float s1 = 0.f, s2 = 0.f, mx = -3.4e38f;
  for (int n = blockIdx.x*4 + (t>>6); n < N; n += gridDim.x*4) {
    float v = x[(size_t)n*64 + c];
    s1 += v; s2 += v*v; mx = fmaxf(mx, v);
  }
  __shared__ float sd[3][256];
  sd[0][t]=s1; sd[1][t]=s2; sd[2][t]=mx;
  __syncthreads();
  if (t < 64) {
    s1 = sd[0][t]+sd[0][t+64]+sd[0][t+128]+sd[0][t+192];
    s2 = sd[1][t]+sd[1][t+64]+sd[1][t+128]+sd[1][t+192];
    mx = fmaxf(fmaxf(sd[2][t],sd[2][t+64]), fmaxf(sd[2][t+128],sd[2][t+192]));
    atomicAdd(&ws[CST + type*192 + c], s1);
    atomicAdd(&ws[CST + type*192 + 64 + c], s2);
    atomicMax((unsigned*)&ws[CST + type*192 + 128 + c], fmap(mx));
  }
}

__device__ __forceinline__ float blocksum128(float v, float* red) {
  int t = threadIdx.x;
  red[t] = v; __syncthreads();
  #pragma unroll
  for (int s = 64; s > 0; s >>= 1) { if (t < s) red[t] += red[t+s]; __syncthreads(); }
  float r = red[0]; __syncthreads();
  return r;
}

// ---------------- critic MLP (one block, 128 threads) ----------------
__global__ __launch_bounds__(128) void k_critic(const float* cW1,const float* cb1,const float* cg1,const float* cbe1,
    const float* cW2,const float* cb2,const float* cg2,const float* cbe2,
    const float* cW3,const float* cb3,const float* cW4,const float* cb4,
    const float* ws, float* out) {
  __shared__ float g[384];
  __shared__ float h1[128];
  __shared__ float h2s[64];
  __shared__ float red[128];
  int t = threadIdx.x;
  if (t < 64) {
    #pragma unroll
    for (int type = 0; type < 2; ++type) {
      float Nf = type ? 30000.f : 8000.f;
      float s1 = ws[CST + type*192 + t];
      float s2 = ws[CST + type*192 + 64 + t];
      unsigned mu_ = __float_as_uint(ws[CST + type*192 + 128 + t]);
      float mean = s1 / Nf;
      float sd = sqrtf(fmaxf((s2 - Nf*mean*mean) / (Nf - 1.f), 0.f));
      g[type*192 + t] = mean;
      g[type*192 + 64 + t] = funmap(mu_);
      g[type*192 + 128 + t] = sd;
    }
  }
  __syncthreads();
  // layer 1: 384 -> 128, LN, relu
  float v = cb1[t];
  for (int k = 0; k < 384; ++k) v += g[k] * cW1[k*128 + t];
  float mu = blocksum128(v, red) * (1.f/128.f);
  float d = v - mu;
  float var = blocksum128(d*d, red) * (1.f/128.f);
  h1[t] = fmaxf(cg1[t]*d*rsqrtf(var + 1e-5f) + cbe1[t], 0.f);
  __syncthreads();
  // layer 2: 128 -> 64, LN, relu
  float v2 = 0.f;
  if (t < 64) { v2 = cb2[t]; for (int k = 0; k < 128; ++k) v2 += h1[k] * cW2[k*64 + t]; }
  float mu2 = blocksum128(t < 64 ? v2 : 0.f, red) * (1.f/64.f);
  float d2 = v2 - mu2;
  float var2 = blocksum128(t < 64 ? d2*d2 : 0.f, red) * (1.f/64.f);
  if (t < 64) h2s[t] = fmaxf(cg2[t]*d2*rsqrtf(var2 + 1e-5f) + cbe2[t], 0.f);
  __syncthreads();
  // layer 3: 64 -> 32, relu; layer 4: 32 -> 1
  float v3 = 0.f;
  if (t < 32) {
    v3 = cb3[t];
    for (int k = 0; k < 64; ++k) v3 += h2s[k] * cW3[k*32 + t];
    v3 = fmaxf(v3, 0.f);
  }
  float s4 = blocksum128(t < 32 ? v3 * cW4[t] : 0.f, red);
  if (t == 0) out[114000] = s4 + cb4[0];
}

extern "C" void kernel_launch(void* const* d_in, const int* in_sizes, int n_in,
                              void* d_out, int out_size, void* d_ws, size_t ws_size,
                              hipStream_t stream) {
  const float* x_agent = (const float*)d_in[0];
  const float* x_track = (const float*)d_in[1];
  const int* s0 = (const int*)d_in[2]; const int* d0_ = (const int*)d_in[3];
  const int* s1 = (const int*)d_in[4]; const int* d1_ = (const int*)d_in[5];
  const int* s2 = (const int*)d_in[6]; const int* d2_ = (const int*)d_in[7];
  const int* s3 = (const int*)d_in[8]; const int* d3_ = (const int*)d_in[9];
  const float* aeW = (const float*)d_in[10]; const float* aeB = (const float*)d_in[11];
  const float* teW = (const float*)d_in[12]; const float* teB = (const float*)d_in[13];
  const float* convW    = (const float*)d_in[14];
  const float* convAsrc = (const float*)d_in[15];
  const float* convAdst = (const float*)d_in[16];
  const float* convBias = (const float*)d_in[17];
  const float* bnG = (const float*)d_in[18]; const float* bnB = (const float*)d_in[19];
  const float* aW1 = (const float*)d_in[20]; const float* ab1 = (const float*)d_in[21];
  const float* ag  = (const float*)d_in[22]; const float* abe = (const float*)d_in[23];
  const float* aW2 = (const float*)d_in[24]; const float* ab2 = (const float*)d_in[25];
  const float* cW1 = (const float*)d_in[26]; const float* cb1 = (const float*)d_in[27];
  const float* cg1 = (const float*)d_in[28]; const float* cbe1 = (const float*)d_in[29];
  const float* cW2 = (const float*)d_in[30]; const float* cb2 = (const float*)d_in[31];
  const float* cg2 = (const float*)d_in[32]; const float* cbe2 = (const float*)d_in[33];
  const float* cW3 = (const float*)d_in[34]; const float* cb3 = (const float*)d_in[35];
  const float* cW4 = (const float*)d_in[36]; const float* cb4 = (const float*)d_in[37];
  float* ws = (float*)d_ws;
  float* out = (float*)d_out;

  k_encoder<<<dim3(NTr, 2), 64, 0, stream>>>(x_agent, x_track, aeW, aeB, teW, teB, ws);

  for (int l = 0; l < 3; ++l) {
    size_t zlen = (l == 0) ? (ZLEN + 384) : ZLEN;   // first layer also zeroes critic stats
    hipMemsetAsync(ws + ZOFF, 0, zlen * sizeof(float), stream);
    k_ald<<<dim3(469, 4), 256, 0, stream>>>(convW, convAdst, ws, l);
    k_h_als<<<dim3(1875, 4), 256, 0, stream>>>(convW, convAsrc, ws, l);
    k_edgeA<<<dim3(586, 4), 256, 0, stream>>>(s0,d0_,s1,d1_,s2,d2_,s3,d3_, ws);
    k_unmap<<<dim3(469, 4), 256, 0, stream>>>(ws);
    k_edgeB<<<dim3(586, 4), 256, 0, stream>>>(s0,d0_,s1,d1_,s2,d2_,s3,d3_, ws);
    k_edgeC<<<dim3(37500, 4), 256, 0, stream>>>(s0,d0_,s1,d1_,s2,d2_,s3,d3_, ws);
    k_relustats<<<dim3(128, 2), 256, 0, stream>>>(convBias, ws, l);
    k_bnnorm<<<dim3(7500, 2), 256, 0, stream>>>(bnG, bnB, ws, l);
  }

  k_criticstats<<<dim3(128, 2), 256, 0, stream>>>(ws);
  k_actor<<<dim3(3750, 2), 256, 0, stream>>>(aW1, ab1, ag, abe, aW2, ab2, ws, out);
  k_critic<<<1, 128, 0, stream>>>(cW1,cb1,cg1,cbe1,cW2,cb2,cg2,cbe2,cW3,cb3,cW4,cb4, ws, out);
}

// Round 2
// 1368.033 us; speedup vs baseline: 1.2351x; 1.2351x over previous
//
#include <hip/hip_runtime.h>
#include <math.h>

#define NAg 8000
#define NTr 30000
#define NE  150000

// ---- workspace layout (float offsets) ----
#define XA_OFF 0          // 8000*64
#define XT_OFF 512000     // 30000*64
#define H0_OFF 2432000    // 8000*256
#define H1_OFF 4480000    // 30000*256
#define H2_OFF 12160000   // 8000*256
#define H3_OFF 14208000   // 30000*256
#define ALS0 21888000
#define ALS1 21920000
#define ALS2 22040000
#define ALS3 22072000
#define ALD0 22192000
#define ALD1 22312000
#define ALD2 22344000
#define ALD3 22464000
#define DEN0 22800000
#define DEN1 22920000
#define DEN2 22952000
#define DEN3 23072000
#define OAACC 23104000    // 8000*64
#define OTACC 23616000    // 30000*64
#define BNST 25536000     // [type][2][64]
#define CST  25536256     // [type][3][64] (sum,sumsq,max-mapped)
#define ZOFF 22800000
#define ZLEN 2736256      // floats zeroed per layer (den,acc,bnstats)

__device__ __forceinline__ float lrelu(float x){ return x >= 0.f ? x : 0.2f*x; }
__device__ __forceinline__ unsigned fmap(float f){ unsigned u=__float_as_uint(f); return (u&0x80000000u)? ~u : (u|0x80000000u); }
__device__ __forceinline__ float funmap(unsigned u){ return (u&0x80000000u)? __uint_as_float(u&0x7FFFFFFFu) : __uint_as_float(~u); }
__device__ __forceinline__ float softplusf(float x){ return fmaxf(x,0.f) + log1pf(expf(-fabsf(x))); }
__device__ __forceinline__ float wred64(float v){
  #pragma unroll
  for (int o=32;o;o>>=1) v += __shfl_xor(v,o);
  return v;
}
__device__ __forceinline__ float wred32(float v){
  #pragma unroll
  for (int o=16;o;o>>=1) v += __shfl_xor(v,o,32);
  return v;
}
__device__ __forceinline__ int selNd(int r){ return (r&1)? NAg : NTr; }
__device__ __forceinline__ int selH(int r){ return r==0?H0_OFF: r==1?H1_OFF: r==2?H2_OFF:H3_OFF; }
__device__ __forceinline__ int selALS(int r){ return r==0?ALS0: r==1?ALS1: r==2?ALS2:ALS3; }
__device__ __forceinline__ int selALD(int r){ return r==0?ALD0: r==1?ALD1: r==2?ALD2:ALD3; }
__device__ __forceinline__ int selDEN(int r){ return r==0?DEN0: r==1?DEN1: r==2?DEN2:DEN3; }
__device__ __forceinline__ float sel4(float4 v, int h){
  float r = h==0 ? v.x : h==1 ? v.y : h==2 ? v.z : v.w;
  return r;
}

// ---------------- encoder: x = relu(X @ W + b) ----------------
__global__ __launch_bounds__(64) void k_encoder(const float* xA, const float* xT,
    const float* aeW, const float* aeB, const float* teW, const float* teB, float* ws) {
  int type = blockIdx.y;
  int n = blockIdx.x;
  int N = type ? NTr : NAg;
  if (n >= N) return;
  int F = type ? 48 : 32;
  const float* X = type ? xT : xA;
  const float* W = type ? teW : aeW;
  const float* B = type ? teB : aeB;
  float* out = ws + (type ? XT_OFF : XA_OFF);
  __shared__ float xs[48];
  int t = threadIdx.x;
  if (t < F) xs[t] = X[n*F + t];
  __syncthreads();
  float acc = B[t];
  for (int k = 0; k < F; ++k) acc += xs[k] * W[k*64 + t];
  out[n*64 + t] = fmaxf(acc, 0.f);
}

// ---------------- al_d[n,h] = x_dst[n,:] . (W @ a_dst[h]) ----------------
__global__ __launch_bounds__(256) void k_ald(const float* convW, const float* convAdst,
                                             float* ws, int layer) {
  int r = blockIdx.y;
  int Nd = selNd(r);
  const float* W  = convW + (size_t)(layer*4 + r)*64*256;
  const float* ad = convAdst + (size_t)(layer*4 + r)*256;
  __shared__ float Wad[64*4];
  int t = threadIdx.x;
  {
    int k = t >> 2, h = t & 3;
    float s = 0.f;
    for (int c = 0; c < 64; ++c) s += W[k*256 + h*64 + c] * ad[h*64 + c];
    Wad[k*4 + h] = s;
  }
  __syncthreads();
  const float* xd = ws + ((r & 1) ? XA_OFF : XT_OFF);  // dst node type
  float* ald = ws + selALD(r);
  int n = blockIdx.x * 64 + (t >> 2);
  if (n >= Nd) return;
  int h = t & 3;
  float s = 0.f;
  for (int k = 0; k < 64; ++k) s += xd[n*64 + k] * Wad[k*4 + h];
  ald[n*4 + h] = s;
}

// ---------------- h = x_src @ W   and   al_s = sum(h * a_src) ----------------
__global__ __launch_bounds__(256) void k_h_als(const float* convW, const float* convAsrc,
                                               float* ws, int layer) {
  int r = blockIdx.y;
  int Ns = (r & 1) ? NTr : NAg;
  int row0 = blockIdx.x * 16;
  if (row0 >= Ns) return;
  const float* W  = convW + (size_t)(layer*4 + r)*64*256;
  const float* as = convAsrc + (size_t)(layer*4 + r)*256;
  const float* xg = ws + ((r & 1) ? XT_OFF : XA_OFF);
  float* h  = ws + selH(r);
  float* als = ws + selALS(r);
  __shared__ float xs[16][64];
  __shared__ float asl[256];
  int t = threadIdx.x;
  asl[t] = as[t];
  #pragma unroll
  for (int i = 0; i < 4; ++i) {
    int lin = i*256 + t;
    xs[lin>>6][lin&63] = xg[(row0 + (lin>>6))*64 + (lin&63)];
  }
  __syncthreads();
  int c0 = t & 63;
  int tr = t >> 6;
  float acc[4][4];
  #pragma unroll
  for (int i=0;i<4;i++){ acc[i][0]=0;acc[i][1]=0;acc[i][2]=0;acc[i][3]=0; }
  const float* Wc = W + c0;
  for (int k4 = 0; k4 < 16; ++k4) {
    float4 xv[4];
    #pragma unroll
    for (int i = 0; i < 4; ++i) xv[i] = *(const float4*)&xs[tr*4+i][k4*4];
    #pragma unroll
    for (int kk = 0; kk < 4; ++kk) {
      int k = k4*4 + kk;
      float w0 = Wc[k*256], w1 = Wc[k*256+64], w2 = Wc[k*256+128], w3 = Wc[k*256+192];
      #pragma unroll
      for (int i = 0; i < 4; ++i) {
        float x = (kk==0)?xv[i].x:(kk==1)?xv[i].y:(kk==2)?xv[i].z:xv[i].w;
        acc[i][0] += x*w0; acc[i][1] += x*w1; acc[i][2] += x*w2; acc[i][3] += x*w3;
      }
    }
  }
  #pragma unroll
  for (int i = 0; i < 4; ++i) {
    int row = row0 + tr*4 + i;
    #pragma unroll
    for (int j = 0; j < 4; ++j) h[(size_t)row*256 + j*64 + c0] = acc[i][j];
  }
  #pragma unroll
  for (int i = 0; i < 4; ++i) {
    #pragma unroll
    for (int j = 0; j < 4; ++j) {
      float v = acc[i][j] * asl[j*64 + c0];
      v = wred64(v);
      if (c0 == 0) als[(row0 + tr*4 + i)*4 + j] = v;
    }
  }
}

// ---------------- edge pass B: den = segment_sum(exp(e)) (no max shift; |e|<~2) ----------------
__global__ __launch_bounds__(256) void k_edgeB(const int* s0,const int* d0_,const int* s1,const int* d1_,
    const int* s2,const int* d2_,const int* s3,const int* d3_, float* ws) {
  int r = blockIdx.y;
  const int* sp = r==0? s0 : r==1? s1 : r==2? s2 : s3;
  const int* dp = r==0? d0_ : r==1? d1_ : r==2? d2_ : d3_;
  int e = blockIdx.x*256 + threadIdx.x;
  if (e >= NE) return;
  int s = sp[e], d = dp[e];
  float4 a4 = *(const float4*)(ws + selALS(r) + (size_t)s*4);
  float4 b4 = *(const float4*)(ws + selALD(r) + (size_t)d*4);
  float* den = ws + selDEN(r) + (size_t)d*4;
  atomicAdd(&den[0], expf(lrelu(a4.x + b4.x)));
  atomicAdd(&den[1], expf(lrelu(a4.y + b4.y)));
  atomicAdd(&den[2], expf(lrelu(a4.z + b4.z)));
  atomicAdd(&den[3], expf(lrelu(a4.w + b4.w)));
}

// ---------------- edge pass C: out[dst,c] += 0.125 * sum_h alpha_h * h[src,h,c] ----------------
// one wave per edge, one lane per channel; each lane computes only ONE head's
// alpha (head = lane&3), then 4 intra-group shuffles broadcast p0..p3.
__global__ __launch_bounds__(256) void k_edgeC(const int* s0,const int* d0_,const int* s1,const int* d1_,
    const int* s2,const int* d2_,const int* s3,const int* d3_, float* ws) {
  int r = blockIdx.y;
  const int* sp = r==0? s0 : r==1? s1 : r==2? s2 : s3;
  const int* dp = r==0? d0_ : r==1? d1_ : r==2? d2_ : d3_;
  int wv = threadIdx.x >> 6, lane = threadIdx.x & 63;
  int e = blockIdx.x*4 + wv;
  int s = sp[e], d = dp[e];
  float4 a4 = *(const float4*)(ws + selALS(r) + (size_t)s*4);
  float4 b4 = *(const float4*)(ws + selALD(r) + (size_t)d*4);
  float4 dn = *(const float4*)(ws + selDEN(r) + (size_t)d*4);
  int hh = lane & 3;
  float ah = sel4(a4, hh), bh = sel4(b4, hh), dh = sel4(dn, hh);
  float pme = expf(lrelu(ah + bh)) / (dh + 1e-16f);
  int base = lane & ~3;
  float p0 = __shfl(pme, base + 0);
  float p1 = __shfl(pme, base + 1);
  float p2 = __shfl(pme, base + 2);
  float p3 = __shfl(pme, base + 3);
  const float* hp = ws + selH(r) + (size_t)s*256;
  float v = p0*hp[lane] + p1*hp[64+lane] + p2*hp[128+lane] + p3*hp[192+lane];
  float* accb = ws + ((r & 1) ? OAACC : OTACC);
  atomicAdd(accb + (size_t)d*64 + lane, 0.125f * v);
}

// ---------------- relu(acc + avg bias) in place + per-channel sum/sumsq ----------------
__global__ __launch_bounds__(256) void k_relustats(const float* convBias, float* ws, int layer) {
  int type = blockIdx.y;
  int N = type ? NTr : NAg;
  float* acc = ws + (type ? OTACC : OAACC);
  int rA = type ? 0 : 1, rB = type ? 2 : 3;
  int t = threadIdx.x;
  int c = t & 63;
  float bavg = 0.5f*(convBias[(layer*4 + rA)*64 + c] + convBias[(layer*4 + rB)*64 + c]);
  float s1 = 0.f, s2 = 0.f;
  for (int n = blockIdx.x*4 + (t>>6); n < N; n += gridDim.x*4) {
    float z = fmaxf(acc[(size_t)n*64 + c] + bavg, 0.f);
    acc[(size_t)n*64 + c] = z;
    s1 += z; s2 += z*z;
  }
  __shared__ float sd[2][256];
  sd[0][t] = s1; sd[1][t] = s2;
  __syncthreads();
  if (t < 64) {
    s1 = sd[0][t] + sd[0][t+64] + sd[0][t+128] + sd[0][t+192];
    s2 = sd[1][t] + sd[1][t+64] + sd[1][t+128] + sd[1][t+192];
    atomicAdd(&ws[BNST + type*128 + c], s1);
    atomicAdd(&ws[BNST + type*128 + 64 + c], s2);
  }
}

// ---------------- batchnorm + residual, writes xa/xt in place ----------------
__global__ __launch_bounds__(256) void k_bnnorm(const float* bnG, const float* bnB, float* ws, int layer) {
  int type = blockIdx.y;
  int N = type ? NTr : NAg;
  float* acc = ws + (type ? OTACC : OAACC);
  float* x = ws + (type ? XT_OFF : XA_OFF);
  int i = blockIdx.x*256 + threadIdx.x;
  if (i >= N*64) return;
  int c = i & 63;
  float Nf = (float)N;
  float s1 = ws[BNST + type*128 + c], s2 = ws[BNST + type*128 + 64 + c];
  float mu = s1/Nf, var = s2/Nf - mu*mu;
  float g = bnG[(layer*2 + type)*64 + c], b = bnB[(layer*2 + type)*64 + c];
  float y = g*(acc[i]-mu)*rsqrtf(var + 1e-5f) + b;
  if (layer > 0) y += x[i];
  x[i] = y;
}

// ---------------- actor heads ----------------
__global__ __launch_bounds__(256) void k_actor(const float* aW1, const float* ab1, const float* ag,
    const float* abe, const float* aW2, const float* ab2, const float* ws, float* out) {
  int type = blockIdx.y;
  int N = type ? NTr : NAg;
  int grp = threadIdx.x >> 5, j = threadIdx.x & 31;
  int n = blockIdx.x*8 + grp;
  if (n >= N) return;
  const float* x = ws + (type ? XT_OFF : XA_OFF) + (size_t)n*64;
  int iA = type ? 2 : 0;
  float vals[2];
  #pragma unroll
  for (int p = 0; p < 2; ++p) {
    int i = iA + p;
    float tv = ab1[i*32 + j];
    for (int k = 0; k < 64; ++k) tv += x[k] * aW1[i*2048 + k*32 + j];
    float mu = wred32(tv) * (1.f/32.f);
    float dz = tv - mu;
    float var = wred32(dz*dz) * (1.f/32.f);
    float hn = fmaxf(ag[i*32+j]*dz*rsqrtf(var + 1e-5f) + abe[i*32+j], 0.f);
    float s = wred32(hn * aW2[i*32 + j]) + ab2[i];
    vals[p] = softplusf(s) + 1.f;
  }
  if (j == 0) {
    int offA = type ? 24000 : 0, offB = type ? 54000 : 8000, offC = type ? 84000 : 16000;
    out[offA + n] = vals[0];
    out[offB + n] = vals[1];
    out[offC + n] = vals[0] / (vals[0] + vals[1]);
  }
}

// ---------------- critic column stats ----------------
__global__ __launch_bounds__(256) void k_criticstats(float* ws) {
  int type = blockIdx.y;
  int N = type ? NTr : NAg;
  const float* x = ws + (type ? XT_OFF : XA_OFF);
  int t = threadIdx.x;
  int c = t & 63;
  float s1 = 0.f, s2 = 0.f, mx = -3.4e38f;
  for (int n = blockIdx.x*4 + (t>>6); n < N; n += gridDim.x*4) {
    float v = x[(size_t)n*64 + c];
    s1 += v; s2 += v*v; mx = fmaxf(mx, v);
  }
  __shared__ float sd[3][256];
  sd[0][t]=s1; sd[1][t]=s2; sd[2][t]=mx;
  __syncthreads();
  if (t < 64) {
    s1 = sd[0][t]+sd[0][t+64]+sd[0][t+128]+sd[0][t+192];
    s2 = sd[1][t]+sd[1][t+64]+sd[1][t+128]+sd[1][t+192];
    mx = fmaxf(fmaxf(sd[2][t],sd[2][t+64]), fmaxf(sd[2][t+128],sd[2][t+192]));
    atomicAdd(&ws[CST + type*192 + c], s1);
    atomicAdd(&ws[CST + type*192 + 64 + c], s2);
    atomicMax((unsigned*)&ws[CST + type*192 + 128 + c], fmap(mx));
  }
}

__device__ __forceinline__ float blocksum128(float v, float* red) {
  int t = threadIdx.x;
  red[t] = v; __syncthreads();
  #pragma unroll
  for (int s = 64; s > 0; s >>= 1) { if (t < s) red[t] += red[t+s]; __syncthreads(); }
  float r = red[0]; __syncthreads();
  return r;
}

// ---------------- critic MLP ----------------
__global__ __launch_bounds__(128) void k_critic(const float* cW1,const float* cb1,const float* cg1,const float* cbe1,
    const float* cW2,const float* cb2,const float* cg2,const float* cbe2,
    const float* cW3,const float* cb3,const float* cW4,const float* cb4,
    const float* ws, float* out) {
  __shared__ float g[384];
  __shared__ float h1[128];
  __shared__ float h2s[64];
  __shared__ float red[128];
  int t = threadIdx.x;
  if (t < 64) {
    #pragma unroll
    for (int type = 0; type < 2; ++type) {
      float Nf = type ? 30000.f : 8000.f;
      float s1 = ws[CST + type*192 + t];
      float s2 = ws[CST + type*192 + 64 + t];
      unsigned mu_ = __float_as_uint(ws[CST + type*192 + 128 + t]);
      float mean = s1 / Nf;
      float sd = sqrtf(fmaxf((s2 - Nf*mean*mean) / (Nf - 1.f), 0.f));
      g[type*192 + t] = mean;
      g[type*192 + 64 + t] = funmap(mu_);
      g[type*192 + 128 + t] = sd;
    }
  }
  __syncthreads();
  float v = cb1[t];
  for (int k = 0; k < 384; ++k) v += g[k] * cW1[k*128 + t];
  float mu = blocksum128(v, red) * (1.f/128.f);
  float d = v - mu;
  float var = blocksum128(d*d, red) * (1.f/128.f);
  h1[t] = fmaxf(cg1[t]*d*rsqrtf(var + 1e-5f) + cbe1[t], 0.f);
  __syncthreads();
  float v2 = 0.f;
  if (t < 64) { v2 = cb2[t]; for (int k = 0; k < 128; ++k) v2 += h1[k] * cW2[k*64 + t]; }
  float mu2 = blocksum128(t < 64 ? v2 : 0.f, red) * (1.f/64.f);
  float d2 = v2 - mu2;
  float var2 = blocksum128(t < 64 ? d2*d2 : 0.f, red) * (1.f/64.f);
  if (t < 64) h2s[t] = fmaxf(cg2[t]*d2*rsqrtf(var2 + 1e-5f) + cbe2[t], 0.f);
  __syncthreads();
  float v3 = 0.f;
  if (t < 32) {
    v3 = cb3[t];
    for (int k = 0; k < 64; ++k) v3 += h2s[k] * cW3[k*32 + t];
    v3 = fmaxf(v3, 0.f);
  }
  float s4 = blocksum128(t < 32 ? v3 * cW4[t] : 0.f, red);
  if (t == 0) out[114000] = s4 + cb4[0];
}

extern "C" void kernel_launch(void* const* d_in, const int* in_sizes, int n_in,
                              void* d_out, int out_size, void* d_ws, size_t ws_size,
                              hipStream_t stream) {
  const float* x_agent = (const float*)d_in[0];
  const float* x_track = (const float*)d_in[1];
  const int* s0 = (const int*)d_in[2]; const int* d0_ = (const int*)d_in[3];
  const int* s1 = (const int*)d_in[4]; const int* d1_ = (const int*)d_in[5];
  const int* s2 = (const int*)d_in[6]; const int* d2_ = (const int*)d_in[7];
  const int* s3 = (const int*)d_in[8]; const int* d3_ = (const int*)d_in[9];
  const float* aeW = (const float*)d_in[10]; const float* aeB = (const float*)d_in[11];
  const float* teW = (const float*)d_in[12]; const float* teB = (const float*)d_in[13];
  const float* convW    = (const float*)d_in[14];
  const float* convAsrc = (const float*)d_in[15];
  const float* convAdst = (const float*)d_in[16];
  const float* convBias = (const float*)d_in[17];
  const float* bnG = (const float*)d_in[18]; const float* bnB = (const float*)d_in[19];
  const float* aW1 = (const float*)d_in[20]; const float* ab1 = (const float*)d_in[21];
  const float* ag  = (const float*)d_in[22]; const float* abe = (const float*)d_in[23];
  const float* aW2 = (const float*)d_in[24]; const float* ab2 = (const float*)d_in[25];
  const float* cW1 = (const float*)d_in[26]; const float* cb1 = (const float*)d_in[27];
  const float* cg1 = (const float*)d_in[28]; const float* cbe1 = (const float*)d_in[29];
  const float* cW2 = (const float*)d_in[30]; const float* cb2 = (const float*)d_in[31];
  const float* cg2 = (const float*)d_in[32]; const float* cbe2 = (const float*)d_in[33];
  const float* cW3 = (const float*)d_in[34]; const float* cb3 = (const float*)d_in[35];
  const float* cW4 = (const float*)d_in[36]; const float* cb4 = (const float*)d_in[37];
  float* ws = (float*)d_ws;
  float* out = (float*)d_out;

  k_encoder<<<dim3(NTr, 2), 64, 0, stream>>>(x_agent, x_track, aeW, aeB, teW, teB, ws);

  for (int l = 0; l < 3; ++l) {
    size_t zlen = (l == 0) ? (ZLEN + 384) : ZLEN;
    hipMemsetAsync(ws + ZOFF, 0, zlen * sizeof(float), stream);
    k_ald<<<dim3(469, 4), 256, 0, stream>>>(convW, convAdst, ws, l);
    k_h_als<<<dim3(1875, 4), 256, 0, stream>>>(convW, convAsrc, ws, l);
    k_edgeB<<<dim3(586, 4), 256, 0, stream>>>(s0,d0_,s1,d1_,s2,d2_,s3,d3_, ws);
    k_edgeC<<<dim3(37500, 4), 256, 0, stream>>>(s0,d0_,s1,d1_,s2,d2_,s3,d3_, ws);
    k_relustats<<<dim3(128, 2), 256, 0, stream>>>(convBias, ws, l);
    k_bnnorm<<<dim3(7500, 2), 256, 0, stream>>>(bnG, bnB, ws, l);
  }

  k_criticstats<<<dim3(128, 2), 256, 0, stream>>>(ws);
  k_actor<<<dim3(3750, 2), 256, 0, stream>>>(aW1, ab1, ag, abe, aW2, ab2, ws, out);
  k_critic<<<1, 128, 0, stream>>>(cW1,cb1,cg1,cbe1,cW2,cb2,cg2,cbe2,cW3,cb3,cW4,cb4, ws, out);
}

// Round 3
// 1300.796 us; speedup vs baseline: 1.2989x; 1.0517x over previous
//
#include <hip/hip_runtime.h>
#include <math.h>

#define NAg 8000
#define NTr 30000
#define NE  150000

// ---- workspace layout (float offsets) ----
#define XA_OFF 0          // 8000*64
#define XT_OFF 512000     // 30000*64
#define H0_OFF 2432000    // 8000*256
#define H1_OFF 4480000    // 30000*256
#define H2_OFF 12160000   // 8000*256
#define H3_OFF 14208000   // 30000*256
#define ALS0 21888000
#define ALS1 21920000
#define ALS2 22040000
#define ALS3 22072000
#define ALD0 22192000
#define ALD1 22312000
#define ALD2 22344000
#define ALD3 22464000
#define DEN0 22800000
#define DEN1 22920000
#define DEN2 22952000
#define DEN3 23072000
#define OAACC 23104000    // 8000*64
#define OTACC 23616000    // 30000*64
#define BNST 25536000     // [type][2][64]
#define CST  25536256     // [type][3][64] (sum,sumsq,max-mapped)
#define ZOFF 22800000
#define ZLEN 2736256      // floats zeroed per layer (den,acc,bnstats)

__device__ __forceinline__ float lrelu(float x){ return x >= 0.f ? x : 0.2f*x; }
__device__ __forceinline__ unsigned fmap(float f){ unsigned u=__float_as_uint(f); return (u&0x80000000u)? ~u : (u|0x80000000u); }
__device__ __forceinline__ float funmap(unsigned u){ return (u&0x80000000u)? __uint_as_float(u&0x7FFFFFFFu) : __uint_as_float(~u); }
__device__ __forceinline__ float softplusf(float x){ return fmaxf(x,0.f) + log1pf(expf(-fabsf(x))); }
__device__ __forceinline__ float wred64(float v){
  #pragma unroll
  for (int o=32;o;o>>=1) v += __shfl_xor(v,o);
  return v;
}
__device__ __forceinline__ float wred32(float v){
  #pragma unroll
  for (int o=16;o;o>>=1) v += __shfl_xor(v,o,32);
  return v;
}
__device__ __forceinline__ int selNd(int r){ return (r&1)? NAg : NTr; }
__device__ __forceinline__ int selH(int r){ return r==0?H0_OFF: r==1?H1_OFF: r==2?H2_OFF:H3_OFF; }
__device__ __forceinline__ int selALS(int r){ return r==0?ALS0: r==1?ALS1: r==2?ALS2:ALS3; }
__device__ __forceinline__ int selALD(int r){ return r==0?ALD0: r==1?ALD1: r==2?ALD2:ALD3; }
__device__ __forceinline__ int selDEN(int r){ return r==0?DEN0: r==1?DEN1: r==2?DEN2:DEN3; }

// ---------------- encoder: x = relu(X @ W + b) ----------------
__global__ __launch_bounds__(64) void k_encoder(const float* xA, const float* xT,
    const float* aeW, const float* aeB, const float* teW, const float* teB, float* ws) {
  int type = blockIdx.y;
  int n = blockIdx.x;
  int N = type ? NTr : NAg;
  if (n >= N) return;
  int F = type ? 48 : 32;
  const float* X = type ? xT : xA;
  const float* W = type ? teW : aeW;
  const float* B = type ? teB : aeB;
  float* out = ws + (type ? XT_OFF : XA_OFF);
  __shared__ float xs[48];
  int t = threadIdx.x;
  if (t < F) xs[t] = X[n*F + t];
  __syncthreads();
  float acc = B[t];
  for (int k = 0; k < F; ++k) acc += xs[k] * W[k*64 + t];
  out[n*64 + t] = fmaxf(acc, 0.f);
}

// ---------------- al_d[n,h] = x_dst[n,:] . (W @ a_dst[h]) ----------------
__global__ __launch_bounds__(256) void k_ald(const float* convW, const float* convAdst,
                                             float* ws, int layer) {
  int r = blockIdx.y;
  int Nd = selNd(r);
  const float* W  = convW + (size_t)(layer*4 + r)*64*256;
  const float* ad = convAdst + (size_t)(layer*4 + r)*256;
  __shared__ float Wad[64*4];
  int t = threadIdx.x;
  {
    int k = t >> 2, h = t & 3;
    float s = 0.f;
    for (int c = 0; c < 64; ++c) s += W[k*256 + h*64 + c] * ad[h*64 + c];
    Wad[k*4 + h] = s;
  }
  __syncthreads();
  const float* xd = ws + ((r & 1) ? XA_OFF : XT_OFF);
  float* ald = ws + selALD(r);
  int n = blockIdx.x * 64 + (t >> 2);
  if (n >= Nd) return;
  int h = t & 3;
  float s = 0.f;
  for (int k = 0; k < 64; ++k) s += xd[n*64 + k] * Wad[k*4 + h];
  ald[n*4 + h] = s;
}

// ---------------- h = x_src @ W   and   al_s = sum(h * a_src) ----------------
__global__ __launch_bounds__(256) void k_h_als(const float* convW, const float* convAsrc,
                                               float* ws, int layer) {
  int r = blockIdx.y;
  int Ns = (r & 1) ? NTr : NAg;
  int row0 = blockIdx.x * 16;
  if (row0 >= Ns) return;
  const float* W  = convW + (size_t)(layer*4 + r)*64*256;
  const float* as = convAsrc + (size_t)(layer*4 + r)*256;
  const float* xg = ws + ((r & 1) ? XT_OFF : XA_OFF);
  float* h  = ws + selH(r);
  float* als = ws + selALS(r);
  __shared__ float xs[16][64];
  __shared__ float asl[256];
  int t = threadIdx.x;
  asl[t] = as[t];
  #pragma unroll
  for (int i = 0; i < 4; ++i) {
    int lin = i*256 + t;
    xs[lin>>6][lin&63] = xg[(row0 + (lin>>6))*64 + (lin&63)];
  }
  __syncthreads();
  int c0 = t & 63;
  int tr = t >> 6;
  float acc[4][4];
  #pragma unroll
  for (int i=0;i<4;i++){ acc[i][0]=0;acc[i][1]=0;acc[i][2]=0;acc[i][3]=0; }
  const float* Wc = W + c0;
  for (int k4 = 0; k4 < 16; ++k4) {
    float4 xv[4];
    #pragma unroll
    for (int i = 0; i < 4; ++i) xv[i] = *(const float4*)&xs[tr*4+i][k4*4];
    #pragma unroll
    for (int kk = 0; kk < 4; ++kk) {
      int k = k4*4 + kk;
      float w0 = Wc[k*256], w1 = Wc[k*256+64], w2 = Wc[k*256+128], w3 = Wc[k*256+192];
      #pragma unroll
      for (int i = 0; i < 4; ++i) {
        float x = (kk==0)?xv[i].x:(kk==1)?xv[i].y:(kk==2)?xv[i].z:xv[i].w;
        acc[i][0] += x*w0; acc[i][1] += x*w1; acc[i][2] += x*w2; acc[i][3] += x*w3;
      }
    }
  }
  #pragma unroll
  for (int i = 0; i < 4; ++i) {
    int row = row0 + tr*4 + i;
    #pragma unroll
    for (int j = 0; j < 4; ++j) h[(size_t)row*256 + j*64 + c0] = acc[i][j];
  }
  #pragma unroll
  for (int i = 0; i < 4; ++i) {
    #pragma unroll
    for (int j = 0; j < 4; ++j) {
      float v = acc[i][j] * asl[j*64 + c0];
      v = wred64(v);
      if (c0 == 0) als[(row0 + tr*4 + i)*4 + j] = v;
    }
  }
}

// ---------------- edge pass B: den = segment_sum(exp(e)) (no max shift; logits small) ----------------
__global__ __launch_bounds__(256) void k_edgeB(const int* s0,const int* d0_,const int* s1,const int* d1_,
    const int* s2,const int* d2_,const int* s3,const int* d3_, float* ws) {
  int r = blockIdx.y;
  const int* sp = r==0? s0 : r==1? s1 : r==2? s2 : s3;
  const int* dp = r==0? d0_ : r==1? d1_ : r==2? d2_ : d3_;
  int e = blockIdx.x*256 + threadIdx.x;
  if (e >= NE) return;
  int s = sp[e], d = dp[e];
  float4 a4 = *(const float4*)(ws + selALS(r) + (size_t)s*4);
  float4 b4 = *(const float4*)(ws + selALD(r) + (size_t)d*4);
  float* den = ws + selDEN(r) + (size_t)d*4;
  atomicAdd(&den[0], expf(lrelu(a4.x + b4.x)));
  atomicAdd(&den[1], expf(lrelu(a4.y + b4.y)));
  atomicAdd(&den[2], expf(lrelu(a4.z + b4.z)));
  atomicAdd(&den[3], expf(lrelu(a4.w + b4.w)));
}

// ---------------- rden: den -> 0.125/(den+1e-16) in place ----------------
__global__ __launch_bounds__(256) void k_rden(float* ws) {
  int r = blockIdx.y;
  int n4 = selNd(r) * 4;
  int i = blockIdx.x*256 + threadIdx.x;
  if (i >= n4) return;
  float* den = ws + selDEN(r);
  den[i] = 0.125f / (den[i] + 1e-16f);
}

// ---------------- edge pass C: acc[dst,c] += sum_h (0.125*alpha_h) * h[src,h,c] ----------------
// one wave per 1 edge-chain, 2 independent edges per wave (ILP for latency hiding);
// lane hh=lane&3 computes one head's alpha; shuffles broadcast within 4-lane group.
__global__ __launch_bounds__(256) void k_edgeC(const int* s0,const int* d0_,const int* s1,const int* d1_,
    const int* s2,const int* d2_,const int* s3,const int* d3_, float* ws) {
  int r = blockIdx.y;
  const int* sp = r==0? s0 : r==1? s1 : r==2? s2 : s3;
  const int* dp = r==0? d0_ : r==1? d1_ : r==2? d2_ : d3_;
  int wv = threadIdx.x >> 6, lane = threadIdx.x & 63;
  int hh = lane & 3;
  int base = lane & ~3;
  int e0 = blockIdx.x*8 + wv*2;
  const float* als = ws + selALS(r);
  const float* ald = ws + selALD(r);
  const float* rdn = ws + selDEN(r);
  const float* hb  = ws + selH(r);
  float* accb = ws + ((r & 1) ? OAACC : OTACC);
  #pragma unroll
  for (int q = 0; q < 2; ++q) {
    int e = e0 + q;
    int s = sp[e], d = dp[e];
    float ah = als[s*4 + hh];
    float bh = ald[d*4 + hh];
    float rdh = rdn[d*4 + hh];
    float pme = __expf(lrelu(ah + bh)) * rdh;
    float p0 = __shfl(pme, base + 0);
    float p1 = __shfl(pme, base + 1);
    float p2 = __shfl(pme, base + 2);
    float p3 = __shfl(pme, base + 3);
    const float* hp = hb + (size_t)s*256;
    float v = p0*hp[lane] + p1*hp[64+lane] + p2*hp[128+lane] + p3*hp[192+lane];
    atomicAdd(accb + (size_t)d*64 + lane, v);
  }
}

// ---------------- relu(acc + avg bias) in place + per-channel sum/sumsq ----------------
__global__ __launch_bounds__(256) void k_relustats(const float* convBias, float* ws, int layer) {
  int type = blockIdx.y;
  int N = type ? NTr : NAg;
  float* acc = ws + (type ? OTACC : OAACC);
  int rA = type ? 0 : 1, rB = type ? 2 : 3;
  int t = threadIdx.x;
  int c = t & 63;
  float bavg = 0.5f*(convBias[(layer*4 + rA)*64 + c] + convBias[(layer*4 + rB)*64 + c]);
  float s1 = 0.f, s2 = 0.f;
  for (int n = blockIdx.x*4 + (t>>6); n < N; n += gridDim.x*4) {
    float z = fmaxf(acc[(size_t)n*64 + c] + bavg, 0.f);
    acc[(size_t)n*64 + c] = z;
    s1 += z; s2 += z*z;
  }
  __shared__ float sd[2][256];
  sd[0][t] = s1; sd[1][t] = s2;
  __syncthreads();
  if (t < 64) {
    s1 = sd[0][t] + sd[0][t+64] + sd[0][t+128] + sd[0][t+192];
    s2 = sd[1][t] + sd[1][t+64] + sd[1][t+128] + sd[1][t+192];
    atomicAdd(&ws[BNST + type*128 + c], s1);
    atomicAdd(&ws[BNST + type*128 + 64 + c], s2);
  }
}

// ---------------- batchnorm + residual, writes xa/xt in place ----------------
__global__ __launch_bounds__(256) void k_bnnorm(const float* bnG, const float* bnB, float* ws, int layer) {
  int type = blockIdx.y;
  int N = type ? NTr : NAg;
  float* acc = ws + (type ? OTACC : OAACC);
  float* x = ws + (type ? XT_OFF : XA_OFF);
  int i = blockIdx.x*256 + threadIdx.x;
  if (i >= N*64) return;
  int c = i & 63;
  float Nf = (float)N;
  float s1 = ws[BNST + type*128 + c], s2 = ws[BNST + type*128 + 64 + c];
  float mu = s1/Nf, var = s2/Nf - mu*mu;
  float g = bnG[(layer*2 + type)*64 + c], b = bnB[(layer*2 + type)*64 + c];
  float y = g*(acc[i]-mu)*rsqrtf(var + 1e-5f) + b;
  if (layer > 0) y += x[i];
  x[i] = y;
}

// ---------------- actor heads ----------------
__global__ __launch_bounds__(256) void k_actor(const float* aW1, const float* ab1, const float* ag,
    const float* abe, const float* aW2, const float* ab2, const float* ws, float* out) {
  int type = blockIdx.y;
  int N = type ? NTr : NAg;
  int grp = threadIdx.x >> 5, j = threadIdx.x & 31;
  int n = blockIdx.x*8 + grp;
  if (n >= N) return;
  const float* x = ws + (type ? XT_OFF : XA_OFF) + (size_t)n*64;
  int iA = type ? 2 : 0;
  float vals[2];
  #pragma unroll
  for (int p = 0; p < 2; ++p) {
    int i = iA + p;
    float tv = ab1[i*32 + j];
    for (int k = 0; k < 64; ++k) tv += x[k] * aW1[i*2048 + k*32 + j];
    float mu = wred32(tv) * (1.f/32.f);
    float dz = tv - mu;
    float var = wred32(dz*dz) * (1.f/32.f);
    float hn = fmaxf(ag[i*32+j]*dz*rsqrtf(var + 1e-5f) + abe[i*32+j], 0.f);
    float s = wred32(hn * aW2[i*32 + j]) + ab2[i];
    vals[p] = softplusf(s) + 1.f;
  }
  if (j == 0) {
    int offA = type ? 24000 : 0, offB = type ? 54000 : 8000, offC = type ? 84000 : 16000;
    out[offA + n] = vals[0];
    out[offB + n] = vals[1];
    out[offC + n] = vals[0] / (vals[0] + vals[1]);
  }
}

// ---------------- critic column stats ----------------
__global__ __launch_bounds__(256) void k_criticstats(float* ws) {
  int type = blockIdx.y;
  int N = type ? NTr : NAg;
  const float* x = ws + (type ? XT_OFF : XA_OFF);
  int t = threadIdx.x;
  int c = t & 63;
  float s1 = 0.f, s2 = 0.f, mx = -3.4e38f;
  for (int n = blockIdx.x*4 + (t>>6); n < N; n += gridDim.x*4) {
    float v = x[(size_t)n*64 + c];
    s1 += v; s2 += v*v; mx = fmaxf(mx, v);
  }
  __shared__ float sd[3][256];
  sd[0][t]=s1; sd[1][t]=s2; sd[2][t]=mx;
  __syncthreads();
  if (t < 64) {
    s1 = sd[0][t]+sd[0][t+64]+sd[0][t+128]+sd[0][t+192];
    s2 = sd[1][t]+sd[1][t+64]+sd[1][t+128]+sd[1][t+192];
    mx = fmaxf(fmaxf(sd[2][t],sd[2][t+64]), fmaxf(sd[2][t+128],sd[2][t+192]));
    atomicAdd(&ws[CST + type*192 + c], s1);
    atomicAdd(&ws[CST + type*192 + 64 + c], s2);
    atomicMax((unsigned*)&ws[CST + type*192 + 128 + c], fmap(mx));
  }
}

__device__ __forceinline__ float blocksum128(float v, float* red) {
  int t = threadIdx.x;
  red[t] = v; __syncthreads();
  #pragma unroll
  for (int s = 64; s > 0; s >>= 1) { if (t < s) red[t] += red[t+s]; __syncthreads(); }
  float r = red[0]; __syncthreads();
  return r;
}

// ---------------- critic MLP ----------------
__global__ __launch_bounds__(128) void k_critic(const float* cW1,const float* cb1,const float* cg1,const float* cbe1,
    const float* cW2,const float* cb2,const float* cg2,const float* cbe2,
    const float* cW3,const float* cb3,const float* cW4,const float* cb4,
    const float* ws, float* out) {
  __shared__ float g[384];
  __shared__ float h1[128];
  __shared__ float h2s[64];
  __shared__ float red[128];
  int t = threadIdx.x;
  if (t < 64) {
    #pragma unroll
    for (int type = 0; type < 2; ++type) {
      float Nf = type ? 30000.f : 8000.f;
      float s1 = ws[CST + type*192 + t];
      float s2 = ws[CST + type*192 + 64 + t];
      unsigned mu_ = __float_as_uint(ws[CST + type*192 + 128 + t]);
      float mean = s1 / Nf;
      float sd = sqrtf(fmaxf((s2 - Nf*mean*mean) / (Nf - 1.f), 0.f));
      g[type*192 + t] = mean;
      g[type*192 + 64 + t] = funmap(mu_);
      g[type*192 + 128 + t] = sd;
    }
  }
  __syncthreads();
  float v = cb1[t];
  for (int k = 0; k < 384; ++k) v += g[k] * cW1[k*128 + t];
  float mu = blocksum128(v, red) * (1.f/128.f);
  float d = v - mu;
  float var = blocksum128(d*d, red) * (1.f/128.f);
  h1[t] = fmaxf(cg1[t]*d*rsqrtf(var + 1e-5f) + cbe1[t], 0.f);
  __syncthreads();
  float v2 = 0.f;
  if (t < 64) { v2 = cb2[t]; for (int k = 0; k < 128; ++k) v2 += h1[k] * cW2[k*64 + t]; }
  float mu2 = blocksum128(t < 64 ? v2 : 0.f, red) * (1.f/64.f);
  float d2 = v2 - mu2;
  float var2 = blocksum128(t < 64 ? d2*d2 : 0.f, red) * (1.f/64.f);
  if (t < 64) h2s[t] = fmaxf(cg2[t]*d2*rsqrtf(var2 + 1e-5f) + cbe2[t], 0.f);
  __syncthreads();
  float v3 = 0.f;
  if (t < 32) {
    v3 = cb3[t];
    for (int k = 0; k < 64; ++k) v3 += h2s[k] * cW3[k*32 + t];
    v3 = fmaxf(v3, 0.f);
  }
  float s4 = blocksum128(t < 32 ? v3 * cW4[t] : 0.f, red);
  if (t == 0) out[114000] = s4 + cb4[0];
}

extern "C" void kernel_launch(void* const* d_in, const int* in_sizes, int n_in,
                              void* d_out, int out_size, void* d_ws, size_t ws_size,
                              hipStream_t stream) {
  const float* x_agent = (const float*)d_in[0];
  const float* x_track = (const float*)d_in[1];
  const int* s0 = (const int*)d_in[2]; const int* d0_ = (const int*)d_in[3];
  const int* s1 = (const int*)d_in[4]; const int* d1_ = (const int*)d_in[5];
  const int* s2 = (const int*)d_in[6]; const int* d2_ = (const int*)d_in[7];
  const int* s3 = (const int*)d_in[8]; const int* d3_ = (const int*)d_in[9];
  const float* aeW = (const float*)d_in[10]; const float* aeB = (const float*)d_in[11];
  const float* teW = (const float*)d_in[12]; const float* teB = (const float*)d_in[13];
  const float* convW    = (const float*)d_in[14];
  const float* convAsrc = (const float*)d_in[15];
  const float* convAdst = (const float*)d_in[16];
  const float* convBias = (const float*)d_in[17];
  const float* bnG = (const float*)d_in[18]; const float* bnB = (const float*)d_in[19];
  const float* aW1 = (const float*)d_in[20]; const float* ab1 = (const float*)d_in[21];
  const float* ag  = (const float*)d_in[22]; const float* abe = (const float*)d_in[23];
  const float* aW2 = (const float*)d_in[24]; const float* ab2 = (const float*)d_in[25];
  const float* cW1 = (const float*)d_in[26]; const float* cb1 = (const float*)d_in[27];
  const float* cg1 = (const float*)d_in[28]; const float* cbe1 = (const float*)d_in[29];
  const float* cW2 = (const float*)d_in[30]; const float* cb2 = (const float*)d_in[31];
  const float* cg2 = (const float*)d_in[32]; const float* cbe2 = (const float*)d_in[33];
  const float* cW3 = (const float*)d_in[34]; const float* cb3 = (const float*)d_in[35];
  const float* cW4 = (const float*)d_in[36]; const float* cb4 = (const float*)d_in[37];
  float* ws = (float*)d_ws;
  float* out = (float*)d_out;

  k_encoder<<<dim3(NTr, 2), 64, 0, stream>>>(x_agent, x_track, aeW, aeB, teW, teB, ws);

  for (int l = 0; l < 3; ++l) {
    size_t zlen = (l == 0) ? (ZLEN + 384) : ZLEN;
    hipMemsetAsync(ws + ZOFF, 0, zlen * sizeof(float), stream);
    k_ald<<<dim3(469, 4), 256, 0, stream>>>(convW, convAdst, ws, l);
    k_h_als<<<dim3(1875, 4), 256, 0, stream>>>(convW, convAsrc, ws, l);
    k_edgeB<<<dim3(586, 4), 256, 0, stream>>>(s0,d0_,s1,d1_,s2,d2_,s3,d3_, ws);
    k_rden<<<dim3(469, 4), 256, 0, stream>>>(ws);
    k_edgeC<<<dim3(18750, 4), 256, 0, stream>>>(s0,d0_,s1,d1_,s2,d2_,s3,d3_, ws);
    k_relustats<<<dim3(128, 2), 256, 0, stream>>>(convBias, ws, l);
    k_bnnorm<<<dim3(7500, 2), 256, 0, stream>>>(bnG, bnB, ws, l);
  }

  k_criticstats<<<dim3(128, 2), 256, 0, stream>>>(ws);
  k_actor<<<dim3(3750, 2), 256, 0, stream>>>(aW1, ab1, ag, abe, aW2, ab2, ws, out);
  k_critic<<<1, 128, 0, stream>>>(cW1,cb1,cg1,cbe1,cW2,cb2,cg2,cbe2,cW3,cb3,cW4,cb4, ws, out);
}

// Round 4
// 1236.159 us; speedup vs baseline: 1.3668x; 1.0523x over previous
//
#include <hip/hip_runtime.h>
#include <math.h>

#define NAg 8000
#define NTr 30000
#define NE  150000

// ---- workspace layout (float offsets) ----
#define XA_OFF 0          // 8000*64
#define XT_OFF 512000     // 30000*64
#define H0_OFF 2432000    // 8000*256
#define H1_OFF 4480000    // 30000*256
#define H2_OFF 12160000   // 8000*256
#define H3_OFF 14208000   // 30000*256
#define ALS0 21888000
#define ALS1 21920000
#define ALS2 22040000
#define ALS3 22072000
#define ALD0 22192000
#define ALD1 22312000
#define ALD2 22344000
#define ALD3 22464000
// CSR region reuses old M/DEN space: 22496000..23104000 (608000 floats free)
#define ESRC_I 22496000   // int offsets into (int*)ws; 4 x 150000 = 600000 ints
#define OAACC 23104000    // 8000*64
#define OTACC 23616000    // 30000*64
#define BNST 25536000     // [type: 0 agent,1 track][2][64]
#define CST  25536256     // [type][3][64] (sum,sumsq,max-mapped)
#define ROWP_I 25536640   // 4 x 30016 ints (row_ptr per relation)
#define CURS_I 25656704   // 4 x 30016 ints (cursors)
#define RELSTRIDE 30016

__device__ __forceinline__ float lrelu(float x){ return x >= 0.f ? x : 0.2f*x; }
__device__ __forceinline__ unsigned fmap(float f){ unsigned u=__float_as_uint(f); return (u&0x80000000u)? ~u : (u|0x80000000u); }
__device__ __forceinline__ float funmap(unsigned u){ return (u&0x80000000u)? __uint_as_float(u&0x7FFFFFFFu) : __uint_as_float(~u); }
__device__ __forceinline__ float softplusf(float x){ return fmaxf(x,0.f) + log1pf(expf(-fabsf(x))); }
__device__ __forceinline__ float wred64(float v){
  #pragma unroll
  for (int o=32;o;o>>=1) v += __shfl_xor(v,o);
  return v;
}
__device__ __forceinline__ float wred32(float v){
  #pragma unroll
  for (int o=16;o;o>>=1) v += __shfl_xor(v,o,32);
  return v;
}
__device__ __forceinline__ int selH(int r){ return r==0?H0_OFF: r==1?H1_OFF: r==2?H2_OFF:H3_OFF; }
__device__ __forceinline__ int selALS(int r){ return r==0?ALS0: r==1?ALS1: r==2?ALS2:ALS3; }
__device__ __forceinline__ int selALD(int r){ return r==0?ALD0: r==1?ALD1: r==2?ALD2:ALD3; }

// ---------------- encoder: x = relu(X @ W + b) ----------------
__global__ __launch_bounds__(64) void k_encoder(const float* xA, const float* xT,
    const float* aeW, const float* aeB, const float* teW, const float* teB, float* ws) {
  int type = blockIdx.y;
  int n = blockIdx.x;
  int N = type ? NTr : NAg;
  if (n >= N) return;
  int F = type ? 48 : 32;
  const float* X = type ? xT : xA;
  const float* W = type ? teW : aeW;
  const float* B = type ? teB : aeB;
  float* out = ws + (type ? XT_OFF : XA_OFF);
  __shared__ float xs[48];
  int t = threadIdx.x;
  if (t < F) xs[t] = X[n*F + t];
  __syncthreads();
  float acc = B[t];
  for (int k = 0; k < F; ++k) acc += xs[k] * W[k*64 + t];
  out[n*64 + t] = fmaxf(acc, 0.f);
}

// ---------------- CSR build: histogram ----------------
__global__ __launch_bounds__(256) void k_hist(const int* d0_,const int* d1_,const int* d2_,const int* d3_,
                                              int* wsi) {
  int r = blockIdx.y;
  const int* dp = r==0? d0_ : r==1? d1_ : r==2? d2_ : d3_;
  int e = blockIdx.x*256 + threadIdx.x;
  if (e >= NE) return;
  atomicAdd(&wsi[ROWP_I + r*RELSTRIDE + dp[e]], 1);
}

// ---------------- CSR build: exclusive scan per relation ----------------
__global__ __launch_bounds__(256) void k_scan(int* wsi) {
  int r = blockIdx.x;
  int n = ((r & 1) ? NAg : NTr) + 1;
  int* rp = wsi + ROWP_I + r*RELSTRIDE;
  __shared__ int part[256];
  int t = threadIdx.x;
  int chunk = (n + 255) / 256;
  int lo = t*chunk, hi = min(lo + chunk, n);
  int s = 0;
  for (int i = lo; i < hi; ++i) s += rp[i];
  part[t] = s;
  __syncthreads();
  if (t == 0) {
    int run = 0;
    for (int i = 0; i < 256; ++i) { int tm = part[i]; part[i] = run; run += tm; }
  }
  __syncthreads();
  int run = part[t];
  for (int i = lo; i < hi; ++i) { int tm = rp[i]; rp[i] = run; run += tm; }
}

// ---------------- CSR build: fill sorted src lists ----------------
__global__ __launch_bounds__(256) void k_fill(const int* s0,const int* d0_,const int* s1,const int* d1_,
    const int* s2,const int* d2_,const int* s3,const int* d3_, int* wsi) {
  int r = blockIdx.y;
  const int* sp = r==0? s0 : r==1? s1 : r==2? s2 : s3;
  const int* dp = r==0? d0_ : r==1? d1_ : r==2? d2_ : d3_;
  int e = blockIdx.x*256 + threadIdx.x;
  if (e >= NE) return;
  int d = dp[e];
  int pos = wsi[ROWP_I + r*RELSTRIDE + d] + atomicAdd(&wsi[CURS_I + r*RELSTRIDE + d], 1);
  wsi[ESRC_I + r*NE + pos] = sp[e];
}

// ---------------- al_d[n,h] = x_dst[n,:] . (W @ a_dst[h]) ----------------
__global__ __launch_bounds__(256) void k_ald(const float* convW, const float* convAdst,
                                             float* ws, int layer) {
  int r = blockIdx.y;
  int Nd = (r & 1) ? NAg : NTr;
  const float* W  = convW + (size_t)(layer*4 + r)*64*256;
  const float* ad = convAdst + (size_t)(layer*4 + r)*256;
  __shared__ float Wad[64*4];
  int t = threadIdx.x;
  {
    int k = t >> 2, h = t & 3;
    float s = 0.f;
    for (int c = 0; c < 64; ++c) s += W[k*256 + h*64 + c] * ad[h*64 + c];
    Wad[k*4 + h] = s;
  }
  __syncthreads();
  const float* xd = ws + ((r & 1) ? XA_OFF : XT_OFF);
  float* ald = ws + selALD(r);
  int n = blockIdx.x * 64 + (t >> 2);
  if (n >= Nd) return;
  int h = t & 3;
  float s = 0.f;
  for (int k = 0; k < 64; ++k) s += xd[n*64 + k] * Wad[k*4 + h];
  ald[n*4 + h] = s;
}

// ---------------- h = x_src @ W   and   al_s = sum(h * a_src) ----------------
__global__ __launch_bounds__(256) void k_h_als(const float* convW, const float* convAsrc,
                                               float* ws, int layer) {
  int r = blockIdx.y;
  int Ns = (r & 1) ? NTr : NAg;
  int row0 = blockIdx.x * 16;
  if (row0 >= Ns) return;
  const float* W  = convW + (size_t)(layer*4 + r)*64*256;
  const float* as = convAsrc + (size_t)(layer*4 + r)*256;
  const float* xg = ws + ((r & 1) ? XT_OFF : XA_OFF);
  float* h  = ws + selH(r);
  float* als = ws + selALS(r);
  __shared__ float xs[16][64];
  __shared__ float asl[256];
  int t = threadIdx.x;
  asl[t] = as[t];
  #pragma unroll
  for (int i = 0; i < 4; ++i) {
    int lin = i*256 + t;
    xs[lin>>6][lin&63] = xg[(row0 + (lin>>6))*64 + (lin&63)];
  }
  __syncthreads();
  int c0 = t & 63;
  int tr = t >> 6;
  float acc[4][4];
  #pragma unroll
  for (int i=0;i<4;i++){ acc[i][0]=0;acc[i][1]=0;acc[i][2]=0;acc[i][3]=0; }
  const float* Wc = W + c0;
  for (int k4 = 0; k4 < 16; ++k4) {
    float4 xv[4];
    #pragma unroll
    for (int i = 0; i < 4; ++i) xv[i] = *(const float4*)&xs[tr*4+i][k4*4];
    #pragma unroll
    for (int kk = 0; kk < 4; ++kk) {
      int k = k4*4 + kk;
      float w0 = Wc[k*256], w1 = Wc[k*256+64], w2 = Wc[k*256+128], w3 = Wc[k*256+192];
      #pragma unroll
      for (int i = 0; i < 4; ++i) {
        float x = (kk==0)?xv[i].x:(kk==1)?xv[i].y:(kk==2)?xv[i].z:xv[i].w;
        acc[i][0] += x*w0; acc[i][1] += x*w1; acc[i][2] += x*w2; acc[i][3] += x*w3;
      }
    }
  }
  #pragma unroll
  for (int i = 0; i < 4; ++i) {
    int row = row0 + tr*4 + i;
    #pragma unroll
    for (int j = 0; j < 4; ++j) h[(size_t)row*256 + j*64 + c0] = acc[i][j];
  }
  #pragma unroll
  for (int i = 0; i < 4; ++i) {
    #pragma unroll
    for (int j = 0; j < 4; ++j) {
      float v = acc[i][j] * asl[j*64 + c0];
      v = wred64(v);
      if (c0 == 0) als[(row0 + tr*4 + i)*4 + j] = v;
    }
  }
}

// ---------------- fused CSR aggregation: softmax-weighted sum + bias + relu + BN stats ----------------
// wave per dst node; out_c = 0.125 * sum_rel sum_h (sum_e exp_e,h * h_e[h,c]) / (sum_e exp_e,h)
__global__ __launch_bounds__(256) void k_agg(const float* convBias, float* ws, int layer) {
  int type = blockIdx.y;                  // 0: track dst (rels 0,2), 1: agent dst (rels 1,3)
  int N = type ? NAg : NTr;
  if (blockIdx.x * 4 >= N) return;        // whole-block guard (grid sized for tracks)
  int t = threadIdx.x, lane = t & 63, hh = lane & 3, base = lane & ~3;
  int node = blockIdx.x*4 + (t >> 6);
  const int* wsi = (const int*)ws;
  float outv = 0.f;
  #pragma unroll
  for (int rr = 0; rr < 2; ++rr) {
    int r = type ? (rr ? 3 : 1) : (rr ? 2 : 0);
    const int* rp = wsi + ROWP_I + r*RELSTRIDE;
    const int* es = wsi + ESRC_I + r*NE;
    const float* als = ws + selALS(r);
    const float* hb  = ws + selH(r);
    float ad = (ws + selALD(r))[node*4 + hh];
    int p = rp[node], p1 = rp[node+1];
    float num0=0.f, num1=0.f, num2=0.f, num3=0.f, den=0.f;
    int sN = (p < p1) ? es[p] : 0;
    while (p < p1) {
      int s = sN;
      ++p;
      sN = (p < p1) ? es[p] : 0;          // prefetch next src index
      float e = __expf(lrelu(als[s*4 + hh] + ad));
      den += e;
      float q0 = __shfl(e, base), q1 = __shfl(e, base+1), q2 = __shfl(e, base+2), q3 = __shfl(e, base+3);
      const float* hp = hb + (size_t)s*256;
      num0 += q0*hp[lane]; num1 += q1*hp[64+lane]; num2 += q2*hp[128+lane]; num3 += q3*hp[192+lane];
    }
    float rd = 1.f/(den + 1e-16f);        // lane hh holds den for head hh
    float r0 = __shfl(rd, base), r1 = __shfl(rd, base+1), r2 = __shfl(rd, base+2), r3 = __shfl(rd, base+3);
    outv += num0*r0 + num1*r1 + num2*r2 + num3*r3;
  }
  int rA = type ? 1 : 0, rB = type ? 3 : 2;
  float bavg = 0.5f*(convBias[(layer*4 + rA)*64 + lane] + convBias[(layer*4 + rB)*64 + lane]);
  float z = fmaxf(outv*0.125f + bavg, 0.f);
  float* acc = ws + (type ? OAACC : OTACC);
  acc[(size_t)node*64 + lane] = z;
  // fused BN column stats (BNST convention: 0 agent, 1 track)
  __shared__ float sd[2][256];
  sd[0][t] = z; sd[1][t] = z*z;
  __syncthreads();
  if (t < 64) {
    float s1 = sd[0][t] + sd[0][t+64] + sd[0][t+128] + sd[0][t+192];
    float s2 = sd[1][t] + sd[1][t+64] + sd[1][t+128] + sd[1][t+192];
    int bt = type ? 0 : 1;
    atomicAdd(&ws[BNST + bt*128 + t], s1);
    atomicAdd(&ws[BNST + bt*128 + 64 + t], s2);
  }
}

// ---------------- batchnorm + residual, writes xa/xt in place ----------------
__global__ __launch_bounds__(256) void k_bnnorm(const float* bnG, const float* bnB, float* ws, int layer) {
  int type = blockIdx.y;                  // 0 agent, 1 track
  int N = type ? NTr : NAg;
  float* acc = ws + (type ? OTACC : OAACC);
  float* x = ws + (type ? XT_OFF : XA_OFF);
  int i = blockIdx.x*256 + threadIdx.x;
  if (i >= N*64) return;
  int c = i & 63;
  float Nf = (float)N;
  float s1 = ws[BNST + type*128 + c], s2 = ws[BNST + type*128 + 64 + c];
  float mu = s1/Nf, var = s2/Nf - mu*mu;
  float g = bnG[(layer*2 + type)*64 + c], b = bnB[(layer*2 + type)*64 + c];
  float y = g*(acc[i]-mu)*rsqrtf(var + 1e-5f) + b;
  if (layer > 0) y += x[i];
  x[i] = y;
}

// ---------------- actor heads ----------------
__global__ __launch_bounds__(256) void k_actor(const float* aW1, const float* ab1, const float* ag,
    const float* abe, const float* aW2, const float* ab2, const float* ws, float* out) {
  int type = blockIdx.y;
  int N = type ? NTr : NAg;
  int grp = threadIdx.x >> 5, j = threadIdx.x & 31;
  int n = blockIdx.x*8 + grp;
  if (n >= N) return;
  const float* x = ws + (type ? XT_OFF : XA_OFF) + (size_t)n*64;
  int iA = type ? 2 : 0;
  float vals[2];
  #pragma unroll
  for (int p = 0; p < 2; ++p) {
    int i = iA + p;
    float tv = ab1[i*32 + j];
    for (int k = 0; k < 64; ++k) tv += x[k] * aW1[i*2048 + k*32 + j];
    float mu = wred32(tv) * (1.f/32.f);
    float dz = tv - mu;
    float var = wred32(dz*dz) * (1.f/32.f);
    float hn = fmaxf(ag[i*32+j]*dz*rsqrtf(var + 1e-5f) + abe[i*32+j], 0.f);
    float s = wred32(hn * aW2[i*32 + j]) + ab2[i];
    vals[p] = softplusf(s) + 1.f;
  }
  if (j == 0) {
    int offA = type ? 24000 : 0, offB = type ? 54000 : 8000, offC = type ? 84000 : 16000;
    out[offA + n] = vals[0];
    out[offB + n] = vals[1];
    out[offC + n] = vals[0] / (vals[0] + vals[1]);
  }
}

// ---------------- critic column stats ----------------
__global__ __launch_bounds__(256) void k_criticstats(float* ws) {
  int type = blockIdx.y;
  int N = type ? NTr : NAg;
  const float* x = ws + (type ? XT_OFF : XA_OFF);
  int t = threadIdx.x;
  int c = t & 63;
  float s1 = 0.f, s2 = 0.f, mx = -3.4e38f;
  for (int n = blockIdx.x*4 + (t>>6); n < N; n += gridDim.x*4) {
    float v = x[(size_t)n*64 + c];
    s1 += v; s2 += v*v; mx = fmaxf(mx, v);
  }
  __shared__ float sd[3][256];
  sd[0][t]=s1; sd[1][t]=s2; sd[2][t]=mx;
  __syncthreads();
  if (t < 64) {
    s1 = sd[0][t]+sd[0][t+64]+sd[0][t+128]+sd[0][t+192];
    s2 = sd[1][t]+sd[1][t+64]+sd[1][t+128]+sd[1][t+192];
    mx = fmaxf(fmaxf(sd[2][t],sd[2][t+64]), fmaxf(sd[2][t+128],sd[2][t+192]));
    atomicAdd(&ws[CST + type*192 + c], s1);
    atomicAdd(&ws[CST + type*192 + 64 + c], s2);
    atomicMax((unsigned*)&ws[CST + type*192 + 128 + c], fmap(mx));
  }
}

__device__ __forceinline__ float blocksum128(float v, float* red) {
  int t = threadIdx.x;
  red[t] = v; __syncthreads();
  #pragma unroll
  for (int s = 64; s > 0; s >>= 1) { if (t < s) red[t] += red[t+s]; __syncthreads(); }
  float r = red[0]; __syncthreads();
  return r;
}

// ---------------- critic MLP ----------------
__global__ __launch_bounds__(128) void k_critic(const float* cW1,const float* cb1,const float* cg1,const float* cbe1,
    const float* cW2,const float* cb2,const float* cg2,const float* cbe2,
    const float* cW3,const float* cb3,const float* cW4,const float* cb4,
    const float* ws, float* out) {
  __shared__ float g[384];
  __shared__ float h1[128];
  __shared__ float h2s[64];
  __shared__ float red[128];
  int t = threadIdx.x;
  if (t < 64) {
    #pragma unroll
    for (int type = 0; type < 2; ++type) {
      float Nf = type ? 30000.f : 8000.f;
      float s1 = ws[CST + type*192 + t];
      float s2 = ws[CST + type*192 + 64 + t];
      unsigned mu_ = __float_as_uint(ws[CST + type*192 + 128 + t]);
      float mean = s1 / Nf;
      float sd = sqrtf(fmaxf((s2 - Nf*mean*mean) / (Nf - 1.f), 0.f));
      g[type*192 + t] = mean;
      g[type*192 + 64 + t] = funmap(mu_);
      g[type*192 + 128 + t] = sd;
    }
  }
  __syncthreads();
  float v = cb1[t];
  for (int k = 0; k < 384; ++k) v += g[k] * cW1[k*128 + t];
  float mu = blocksum128(v, red) * (1.f/128.f);
  float d = v - mu;
  float var = blocksum128(d*d, red) * (1.f/128.f);
  h1[t] = fmaxf(cg1[t]*d*rsqrtf(var + 1e-5f) + cbe1[t], 0.f);
  __syncthreads();
  float v2 = 0.f;
  if (t < 64) { v2 = cb2[t]; for (int k = 0; k < 128; ++k) v2 += h1[k] * cW2[k*64 + t]; }
  float mu2 = blocksum128(t < 64 ? v2 : 0.f, red) * (1.f/64.f);
  float d2 = v2 - mu2;
  float var2 = blocksum128(t < 64 ? d2*d2 : 0.f, red) * (1.f/64.f);
  if (t < 64) h2s[t] = fmaxf(cg2[t]*d2*rsqrtf(var2 + 1e-5f) + cbe2[t], 0.f);
  __syncthreads();
  float v3 = 0.f;
  if (t < 32) {
    v3 = cb3[t];
    for (int k = 0; k < 64; ++k) v3 += h2s[k] * cW3[k*32 + t];
    v3 = fmaxf(v3, 0.f);
  }
  float s4 = blocksum128(t < 32 ? v3 * cW4[t] : 0.f, red);
  if (t == 0) out[114000] = s4 + cb4[0];
}

extern "C" void kernel_launch(void* const* d_in, const int* in_sizes, int n_in,
                              void* d_out, int out_size, void* d_ws, size_t ws_size,
                              hipStream_t stream) {
  const float* x_agent = (const float*)d_in[0];
  const float* x_track = (const float*)d_in[1];
  const int* s0 = (const int*)d_in[2]; const int* d0_ = (const int*)d_in[3];
  const int* s1 = (const int*)d_in[4]; const int* d1_ = (const int*)d_in[5];
  const int* s2 = (const int*)d_in[6]; const int* d2_ = (const int*)d_in[7];
  const int* s3 = (const int*)d_in[8]; const int* d3_ = (const int*)d_in[9];
  const float* aeW = (const float*)d_in[10]; const float* aeB = (const float*)d_in[11];
  const float* teW = (const float*)d_in[12]; const float* teB = (const float*)d_in[13];
  const float* convW    = (const float*)d_in[14];
  const float* convAsrc = (const float*)d_in[15];
  const float* convAdst = (const float*)d_in[16];
  const float* convBias = (const float*)d_in[17];
  const float* bnG = (const float*)d_in[18]; const float* bnB = (const float*)d_in[19];
  const float* aW1 = (const float*)d_in[20]; const float* ab1 = (const float*)d_in[21];
  const float* ag  = (const float*)d_in[22]; const float* abe = (const float*)d_in[23];
  const float* aW2 = (const float*)d_in[24]; const float* ab2 = (const float*)d_in[25];
  const float* cW1 = (const float*)d_in[26]; const float* cb1 = (const float*)d_in[27];
  const float* cg1 = (const float*)d_in[28]; const float* cbe1 = (const float*)d_in[29];
  const float* cW2 = (const float*)d_in[30]; const float* cb2 = (const float*)d_in[31];
  const float* cg2 = (const float*)d_in[32]; const float* cbe2 = (const float*)d_in[33];
  const float* cW3 = (const float*)d_in[34]; const float* cb3 = (const float*)d_in[35];
  const float* cW4 = (const float*)d_in[36]; const float* cb4 = (const float*)d_in[37];
  float* ws = (float*)d_ws;
  int* wsi = (int*)d_ws;
  float* out = (float*)d_out;

  // zero CSR counters (rowp+curs) and CST
  hipMemsetAsync(wsi + ROWP_I, 0, (size_t)240128 * sizeof(int), stream);
  hipMemsetAsync(ws + CST, 0, (size_t)384 * sizeof(float), stream);

  k_encoder<<<dim3(NTr, 2), 64, 0, stream>>>(x_agent, x_track, aeW, aeB, teW, teB, ws);

  // CSR build (once per call; reused across 3 layers)
  k_hist<<<dim3(586, 4), 256, 0, stream>>>(d0_, d1_, d2_, d3_, wsi);
  k_scan<<<dim3(4), 256, 0, stream>>>(wsi);
  k_fill<<<dim3(586, 4), 256, 0, stream>>>(s0,d0_,s1,d1_,s2,d2_,s3,d3_, wsi);

  for (int l = 0; l < 3; ++l) {
    hipMemsetAsync(ws + BNST, 0, (size_t)256 * sizeof(float), stream);
    k_ald<<<dim3(469, 4), 256, 0, stream>>>(convW, convAdst, ws, l);
    k_h_als<<<dim3(1875, 4), 256, 0, stream>>>(convW, convAsrc, ws, l);
    k_agg<<<dim3(7500, 2), 256, 0, stream>>>(convBias, ws, l);
    k_bnnorm<<<dim3(7500, 2), 256, 0, stream>>>(bnG, bnB, ws, l);
  }

  k_criticstats<<<dim3(128, 2), 256, 0, stream>>>(ws);
  k_actor<<<dim3(3750, 2), 256, 0, stream>>>(aW1, ab1, ag, abe, aW2, ab2, ws, out);
  k_critic<<<1, 128, 0, stream>>>(cW1,cb1,cg1,cbe1,cW2,cb2,cg2,cbe2,cW3,cb3,cW4,cb4, ws, out);
}

// Round 5
// 1220.882 us; speedup vs baseline: 1.3839x; 1.0125x over previous
//
#include <hip/hip_runtime.h>
#include <math.h>

#define NAg 8000
#define NTr 30000
#define NE  150000

// ---- workspace layout (float offsets) ----
#define XA_OFF 0          // 8000*64
#define XT_OFF 512000     // 30000*64
#define H0_OFF 2432000    // 8000*256
#define H1_OFF 4480000    // 30000*256
#define H2_OFF 12160000   // 8000*256
#define H3_OFF 14208000   // 30000*256
#define ALS0 21888000
#define ALS1 21920000
#define ALS2 22040000
#define ALS3 22072000
#define ALD0 22192000
#define ALD1 22312000
#define ALD2 22344000
#define ALD3 22464000
#define ESRC_I 22496000   // int offsets into (int*)ws; 4 x 150000 = 600000 ints
#define OAACC 23104000    // 8000*64
#define OTACC 23616000    // 30000*64
#define BNST 25536000     // [type: 0 agent,1 track][2][64]
#define CST  25536256     // [type][3][64] (sum,sumsq,max-mapped)
#define ROWP_I 25536640   // 4 x 30016 ints (row_ptr per relation)
#define CURS_I 25656704   // 4 x 30016 ints (cursors)
#define RELSTRIDE 30016

__device__ __forceinline__ float lrelu(float x){ return x >= 0.f ? x : 0.2f*x; }
__device__ __forceinline__ unsigned fmap(float f){ unsigned u=__float_as_uint(f); return (u&0x80000000u)? ~u : (u|0x80000000u); }
__device__ __forceinline__ float funmap(unsigned u){ return (u&0x80000000u)? __uint_as_float(u&0x7FFFFFFFu) : __uint_as_float(~u); }
__device__ __forceinline__ float softplusf(float x){ return fmaxf(x,0.f) + log1pf(expf(-fabsf(x))); }
__device__ __forceinline__ float wred64(float v){
  #pragma unroll
  for (int o=32;o;o>>=1) v += __shfl_xor(v,o);
  return v;
}
__device__ __forceinline__ float wred32(float v){
  #pragma unroll
  for (int o=16;o;o>>=1) v += __shfl_xor(v,o,32);
  return v;
}
__device__ __forceinline__ int selH(int r){ return r==0?H0_OFF: r==1?H1_OFF: r==2?H2_OFF:H3_OFF; }
__device__ __forceinline__ int selALS(int r){ return r==0?ALS0: r==1?ALS1: r==2?ALS2:ALS3; }
__device__ __forceinline__ int selALD(int r){ return r==0?ALD0: r==1?ALD1: r==2?ALD2:ALD3; }

// ---------------- encoder: x = relu(X @ W + b) ----------------
__global__ __launch_bounds__(64) void k_encoder(const float* xA, const float* xT,
    const float* aeW, const float* aeB, const float* teW, const float* teB, float* ws) {
  int type = blockIdx.y;
  int n = blockIdx.x;
  int N = type ? NTr : NAg;
  if (n >= N) return;
  int F = type ? 48 : 32;
  const float* X = type ? xT : xA;
  const float* W = type ? teW : aeW;
  const float* B = type ? teB : aeB;
  float* out = ws + (type ? XT_OFF : XA_OFF);
  __shared__ float xs[48];
  int t = threadIdx.x;
  if (t < F) xs[t] = X[n*F + t];
  __syncthreads();
  float acc = B[t];
  for (int k = 0; k < F; ++k) acc += xs[k] * W[k*64 + t];
  out[n*64 + t] = fmaxf(acc, 0.f);
}

// ---------------- CSR build: histogram ----------------
__global__ __launch_bounds__(256) void k_hist(const int* d0_,const int* d1_,const int* d2_,const int* d3_,
                                              int* wsi) {
  int r = blockIdx.y;
  const int* dp = r==0? d0_ : r==1? d1_ : r==2? d2_ : d3_;
  int e = blockIdx.x*256 + threadIdx.x;
  if (e >= NE) return;
  atomicAdd(&wsi[ROWP_I + r*RELSTRIDE + dp[e]], 1);
}

// ---------------- CSR build: exclusive scan per relation ----------------
__global__ __launch_bounds__(256) void k_scan(int* wsi) {
  int r = blockIdx.x;
  int n = ((r & 1) ? NAg : NTr) + 1;
  int* rp = wsi + ROWP_I + r*RELSTRIDE;
  __shared__ int part[256];
  int t = threadIdx.x;
  int chunk = (n + 255) / 256;
  int lo = t*chunk, hi = min(lo + chunk, n);
  int s = 0;
  for (int i = lo; i < hi; ++i) s += rp[i];
  part[t] = s;
  __syncthreads();
  if (t == 0) {
    int run = 0;
    for (int i = 0; i < 256; ++i) { int tm = part[i]; part[i] = run; run += tm; }
  }
  __syncthreads();
  int run = part[t];
  for (int i = lo; i < hi; ++i) { int tm = rp[i]; rp[i] = run; run += tm; }
}

// ---------------- CSR build: fill sorted src lists ----------------
__global__ __launch_bounds__(256) void k_fill(const int* s0,const int* d0_,const int* s1,const int* d1_,
    const int* s2,const int* d2_,const int* s3,const int* d3_, int* wsi) {
  int r = blockIdx.y;
  const int* sp = r==0? s0 : r==1? s1 : r==2? s2 : s3;
  const int* dp = r==0? d0_ : r==1? d1_ : r==2? d2_ : d3_;
  int e = blockIdx.x*256 + threadIdx.x;
  if (e >= NE) return;
  int d = dp[e];
  int pos = wsi[ROWP_I + r*RELSTRIDE + d] + atomicAdd(&wsi[CURS_I + r*RELSTRIDE + d], 1);
  wsi[ESRC_I + r*NE + pos] = sp[e];
}

// ---------------- al_d[n,h] = x_dst[n,:] . (W @ a_dst[h]) ----------------
__global__ __launch_bounds__(256) void k_ald(const float* convW, const float* convAdst,
                                             float* ws, int layer) {
  int r = blockIdx.y;
  int Nd = (r & 1) ? NAg : NTr;
  const float* W  = convW + (size_t)(layer*4 + r)*64*256;
  const float* ad = convAdst + (size_t)(layer*4 + r)*256;
  __shared__ float Wad[64*4];
  int t = threadIdx.x;
  {
    int k = t >> 2, h = t & 3;
    float s = 0.f;
    for (int c = 0; c < 64; ++c) s += W[k*256 + h*64 + c] * ad[h*64 + c];
    Wad[k*4 + h] = s;
  }
  __syncthreads();
  const float* xd = ws + ((r & 1) ? XA_OFF : XT_OFF);
  float* ald = ws + selALD(r);
  int n = blockIdx.x * 64 + (t >> 2);
  if (n >= Nd) return;
  int h = t & 3;
  float s = 0.f;
  for (int k = 0; k < 64; ++k) s += xd[n*64 + k] * Wad[k*4 + h];
  ald[n*4 + h] = s;
}

// ---------------- h = x_src @ W   and   al_s = sum(h * a_src) ----------------
__global__ __launch_bounds__(256) void k_h_als(const float* convW, const float* convAsrc,
                                               float* ws, int layer) {
  int r = blockIdx.y;
  int Ns = (r & 1) ? NTr : NAg;
  int row0 = blockIdx.x * 16;
  if (row0 >= Ns) return;
  const float* W  = convW + (size_t)(layer*4 + r)*64*256;
  const float* as = convAsrc + (size_t)(layer*4 + r)*256;
  const float* xg = ws + ((r & 1) ? XT_OFF : XA_OFF);
  float* h  = ws + selH(r);
  float* als = ws + selALS(r);
  __shared__ float xs[16][64];
  __shared__ float asl[256];
  int t = threadIdx.x;
  asl[t] = as[t];
  #pragma unroll
  for (int i = 0; i < 4; ++i) {
    int lin = i*256 + t;
    xs[lin>>6][lin&63] = xg[(row0 + (lin>>6))*64 + (lin&63)];
  }
  __syncthreads();
  int c0 = t & 63;
  int tr = t >> 6;
  float acc[4][4];
  #pragma unroll
  for (int i=0;i<4;i++){ acc[i][0]=0;acc[i][1]=0;acc[i][2]=0;acc[i][3]=0; }
  const float* Wc = W + c0;
  for (int k4 = 0; k4 < 16; ++k4) {
    float4 xv[4];
    #pragma unroll
    for (int i = 0; i < 4; ++i) xv[i] = *(const float4*)&xs[tr*4+i][k4*4];
    #pragma unroll
    for (int kk = 0; kk < 4; ++kk) {
      int k = k4*4 + kk;
      float w0 = Wc[k*256], w1 = Wc[k*256+64], w2 = Wc[k*256+128], w3 = Wc[k*256+192];
      #pragma unroll
      for (int i = 0; i < 4; ++i) {
        float x = (kk==0)?xv[i].x:(kk==1)?xv[i].y:(kk==2)?xv[i].z:xv[i].w;
        acc[i][0] += x*w0; acc[i][1] += x*w1; acc[i][2] += x*w2; acc[i][3] += x*w3;
      }
    }
  }
  #pragma unroll
  for (int i = 0; i < 4; ++i) {
    int row = row0 + tr*4 + i;
    #pragma unroll
    for (int j = 0; j < 4; ++j) h[(size_t)row*256 + j*64 + c0] = acc[i][j];
  }
  #pragma unroll
  for (int i = 0; i < 4; ++i) {
    #pragma unroll
    for (int j = 0; j < 4; ++j) {
      float v = acc[i][j] * asl[j*64 + c0];
      v = wred64(v);
      if (c0 == 0) als[(row0 + tr*4 + i)*4 + j] = v;
    }
  }
}

// ---------------- fused CSR aggregation (4-edge unrolled for MLP) ----------------
// wave per dst node; out_c = 0.125 * sum_rel sum_h (sum_e exp_e,h * h_e[h,c]) / (sum_e exp_e,h)
__global__ __launch_bounds__(256) void k_agg(const float* convBias, float* ws, int layer) {
  int type = blockIdx.y;                  // 0: track dst (rels 0,2), 1: agent dst (rels 1,3)
  int N = type ? NAg : NTr;
  if (blockIdx.x * 4 >= N) return;
  int t = threadIdx.x, lane = t & 63, hh = lane & 3, base = lane & ~3;
  int node = blockIdx.x*4 + (t >> 6);
  const int* wsi = (const int*)ws;
  float outv = 0.f;
  #pragma unroll
  for (int rr = 0; rr < 2; ++rr) {
    int r = type ? (rr ? 3 : 1) : (rr ? 2 : 0);
    const int* rp = wsi + ROWP_I + r*RELSTRIDE;
    const int* es = wsi + ESRC_I + r*NE;
    const float* als = ws + selALS(r);
    const float* hb  = ws + selH(r);
    float ad = (ws + selALD(r))[node*4 + hh];
    int p = rp[node], p1 = rp[node+1];
    float num0=0.f, num1=0.f, num2=0.f, num3=0.f, den=0.f;
    // 4-edge chunks: issue all 20 loads before any dependent math
    for (; p + 4 <= p1; p += 4) {
      int sa = es[p], sb = es[p+1], sc = es[p+2], sd4 = es[p+3];
      const float* hpa = hb + (size_t)sa*256;
      const float* hpb = hb + (size_t)sb*256;
      const float* hpc = hb + (size_t)sc*256;
      const float* hpd = hb + (size_t)sd4*256;
      float la = als[sa*4+hh], lb = als[sb*4+hh], lc = als[sc*4+hh], ld = als[sd4*4+hh];
      float ha0=hpa[lane], ha1=hpa[64+lane], ha2=hpa[128+lane], ha3=hpa[192+lane];
      float hb0=hpb[lane], hb1=hpb[64+lane], hb2=hpb[128+lane], hb3=hpb[192+lane];
      float hc0=hpc[lane], hc1=hpc[64+lane], hc2=hpc[128+lane], hc3=hpc[192+lane];
      float hd0=hpd[lane], hd1=hpd[64+lane], hd2=hpd[128+lane], hd3=hpd[192+lane];
      float ea = __expf(lrelu(la + ad));
      float eb = __expf(lrelu(lb + ad));
      float ec = __expf(lrelu(lc + ad));
      float ed = __expf(lrelu(ld + ad));
      den += (ea+eb)+(ec+ed);
      float qa0=__shfl(ea,base), qa1=__shfl(ea,base+1), qa2=__shfl(ea,base+2), qa3=__shfl(ea,base+3);
      float qb0=__shfl(eb,base), qb1=__shfl(eb,base+1), qb2=__shfl(eb,base+2), qb3=__shfl(eb,base+3);
      float qc0=__shfl(ec,base), qc1=__shfl(ec,base+1), qc2=__shfl(ec,base+2), qc3=__shfl(ec,base+3);
      float qd0=__shfl(ed,base), qd1=__shfl(ed,base+1), qd2=__shfl(ed,base+2), qd3=__shfl(ed,base+3);
      num0 += qa0*ha0 + qb0*hb0 + qc0*hc0 + qd0*hd0;
      num1 += qa1*ha1 + qb1*hb1 + qc1*hc1 + qd1*hd1;
      num2 += qa2*ha2 + qb2*hb2 + qc2*hc2 + qd2*hd2;
      num3 += qa3*ha3 + qb3*hb3 + qc3*hc3 + qd3*hd3;
    }
    for (; p < p1; ++p) {
      int s = es[p];
      const float* hp = hb + (size_t)s*256;
      float e = __expf(lrelu(als[s*4 + hh] + ad));
      den += e;
      float q0 = __shfl(e, base), q1 = __shfl(e, base+1), q2 = __shfl(e, base+2), q3 = __shfl(e, base+3);
      num0 += q0*hp[lane]; num1 += q1*hp[64+lane]; num2 += q2*hp[128+lane]; num3 += q3*hp[192+lane];
    }
    float rd = 1.f/(den + 1e-16f);        // lane hh holds den for head hh
    float r0 = __shfl(rd, base), r1 = __shfl(rd, base+1), r2 = __shfl(rd, base+2), r3 = __shfl(rd, base+3);
    outv += num0*r0 + num1*r1 + num2*r2 + num3*r3;
  }
  int rA = type ? 1 : 0, rB = type ? 3 : 2;
  float bavg = 0.5f*(convBias[(layer*4 + rA)*64 + lane] + convBias[(layer*4 + rB)*64 + lane]);
  float z = fmaxf(outv*0.125f + bavg, 0.f);
  float* acc = ws + (type ? OAACC : OTACC);
  acc[(size_t)node*64 + lane] = z;
  __shared__ float sdm[2][256];
  sdm[0][t] = z; sdm[1][t] = z*z;
  __syncthreads();
  if (t < 64) {
    float s1 = sdm[0][t] + sdm[0][t+64] + sdm[0][t+128] + sdm[0][t+192];
    float s2 = sdm[1][t] + sdm[1][t+64] + sdm[1][t+128] + sdm[1][t+192];
    int bt = type ? 0 : 1;
    atomicAdd(&ws[BNST + bt*128 + t], s1);
    atomicAdd(&ws[BNST + bt*128 + 64 + t], s2);
  }
}

// ---------------- batchnorm + residual, writes xa/xt in place ----------------
__global__ __launch_bounds__(256) void k_bnnorm(const float* bnG, const float* bnB, float* ws, int layer) {
  int type = blockIdx.y;                  // 0 agent, 1 track
  int N = type ? NTr : NAg;
  float* acc = ws + (type ? OTACC : OAACC);
  float* x = ws + (type ? XT_OFF : XA_OFF);
  int i = blockIdx.x*256 + threadIdx.x;
  if (i >= N*64) return;
  int c = i & 63;
  float Nf = (float)N;
  float s1 = ws[BNST + type*128 + c], s2 = ws[BNST + type*128 + 64 + c];
  float mu = s1/Nf, var = s2/Nf - mu*mu;
  float g = bnG[(layer*2 + type)*64 + c], b = bnB[(layer*2 + type)*64 + c];
  float y = g*(acc[i]-mu)*rsqrtf(var + 1e-5f) + b;
  if (layer > 0) y += x[i];
  x[i] = y;
}

// ---------------- actor heads ----------------
__global__ __launch_bounds__(256) void k_actor(const float* aW1, const float* ab1, const float* ag,
    const float* abe, const float* aW2, const float* ab2, const float* ws, float* out) {
  int type = blockIdx.y;
  int N = type ? NTr : NAg;
  int grp = threadIdx.x >> 5, j = threadIdx.x & 31;
  int n = blockIdx.x*8 + grp;
  if (n >= N) return;
  const float* x = ws + (type ? XT_OFF : XA_OFF) + (size_t)n*64;
  int iA = type ? 2 : 0;
  float vals[2];
  #pragma unroll
  for (int p = 0; p < 2; ++p) {
    int i = iA + p;
    float tv = ab1[i*32 + j];
    for (int k = 0; k < 64; ++k) tv += x[k] * aW1[i*2048 + k*32 + j];
    float mu = wred32(tv) * (1.f/32.f);
    float dz = tv - mu;
    float var = wred32(dz*dz) * (1.f/32.f);
    float hn = fmaxf(ag[i*32+j]*dz*rsqrtf(var + 1e-5f) + abe[i*32+j], 0.f);
    float s = wred32(hn * aW2[i*32 + j]) + ab2[i];
    vals[p] = softplusf(s) + 1.f;
  }
  if (j == 0) {
    int offA = type ? 24000 : 0, offB = type ? 54000 : 8000, offC = type ? 84000 : 16000;
    out[offA + n] = vals[0];
    out[offB + n] = vals[1];
    out[offC + n] = vals[0] / (vals[0] + vals[1]);
  }
}

// ---------------- critic column stats ----------------
__global__ __launch_bounds__(256) void k_criticstats(float* ws) {
  int type = blockIdx.y;
  int N = type ? NTr : NAg;
  const float* x = ws + (type ? XT_OFF : XA_OFF);
  int t = threadIdx.x;
  int c = t & 63;
  float s1 = 0.f, s2 = 0.f, mx = -3.4e38f;
  for (int n = blockIdx.x*4 + (t>>6); n < N; n += gridDim.x*4) {
    float v = x[(size_t)n*64 + c];
    s1 += v; s2 += v*v; mx = fmaxf(mx, v);
  }
  __shared__ float sd[3][256];
  sd[0][t]=s1; sd[1][t]=s2; sd[2][t]=mx;
  __syncthreads();
  if (t < 64) {
    s1 = sd[0][t]+sd[0][t+64]+sd[0][t+128]+sd[0][t+192];
    s2 = sd[1][t]+sd[1][t+64]+sd[1][t+128]+sd[1][t+192];
    mx = fmaxf(fmaxf(sd[2][t],sd[2][t+64]), fmaxf(sd[2][t+128],sd[2][t+192]));
    atomicAdd(&ws[CST + type*192 + c], s1);
    atomicAdd(&ws[CST + type*192 + 64 + c], s2);
    atomicMax((unsigned*)&ws[CST + type*192 + 128 + c], fmap(mx));
  }
}

__device__ __forceinline__ float blocksum128(float v, float* red) {
  int t = threadIdx.x;
  red[t] = v; __syncthreads();
  #pragma unroll
  for (int s = 64; s > 0; s >>= 1) { if (t < s) red[t] += red[t+s]; __syncthreads(); }
  float r = red[0]; __syncthreads();
  return r;
}

// ---------------- critic MLP ----------------
__global__ __launch_bounds__(128) void k_critic(const float* cW1,const float* cb1,const float* cg1,const float* cbe1,
    const float* cW2,const float* cb2,const float* cg2,const float* cbe2,
    const float* cW3,const float* cb3,const float* cW4,const float* cb4,
    const float* ws, float* out) {
  __shared__ float g[384];
  __shared__ float h1[128];
  __shared__ float h2s[64];
  __shared__ float red[128];
  int t = threadIdx.x;
  if (t < 64) {
    #pragma unroll
    for (int type = 0; type < 2; ++type) {
      float Nf = type ? 30000.f : 8000.f;
      float s1 = ws[CST + type*192 + t];
      float s2 = ws[CST + type*192 + 64 + t];
      unsigned mu_ = __float_as_uint(ws[CST + type*192 + 128 + t]);
      float mean = s1 / Nf;
      float sd = sqrtf(fmaxf((s2 - Nf*mean*mean) / (Nf - 1.f), 0.f));
      g[type*192 + t] = mean;
      g[type*192 + 64 + t] = funmap(mu_);
      g[type*192 + 128 + t] = sd;
    }
  }
  __syncthreads();
  float v = cb1[t];
  for (int k = 0; k < 384; ++k) v += g[k] * cW1[k*128 + t];
  float mu = blocksum128(v, red) * (1.f/128.f);
  float d = v - mu;
  float var = blocksum128(d*d, red) * (1.f/128.f);
  h1[t] = fmaxf(cg1[t]*d*rsqrtf(var + 1e-5f) + cbe1[t], 0.f);
  __syncthreads();
  float v2 = 0.f;
  if (t < 64) { v2 = cb2[t]; for (int k = 0; k < 128; ++k) v2 += h1[k] * cW2[k*64 + t]; }
  float mu2 = blocksum128(t < 64 ? v2 : 0.f, red) * (1.f/64.f);
  float d2 = v2 - mu2;
  float var2 = blocksum128(t < 64 ? d2*d2 : 0.f, red) * (1.f/64.f);
  if (t < 64) h2s[t] = fmaxf(cg2[t]*d2*rsqrtf(var2 + 1e-5f) + cbe2[t], 0.f);
  __syncthreads();
  float v3 = 0.f;
  if (t < 32) {
    v3 = cb3[t];
    for (int k = 0; k < 64; ++k) v3 += h2s[k] * cW3[k*32 + t];
    v3 = fmaxf(v3, 0.f);
  }
  float s4 = blocksum128(t < 32 ? v3 * cW4[t] : 0.f, red);
  if (t == 0) out[114000] = s4 + cb4[0];
}

extern "C" void kernel_launch(void* const* d_in, const int* in_sizes, int n_in,
                              void* d_out, int out_size, void* d_ws, size_t ws_size,
                              hipStream_t stream) {
  const float* x_agent = (const float*)d_in[0];
  const float* x_track = (const float*)d_in[1];
  const int* s0 = (const int*)d_in[2]; const int* d0_ = (const int*)d_in[3];
  const int* s1 = (const int*)d_in[4]; const int* d1_ = (const int*)d_in[5];
  const int* s2 = (const int*)d_in[6]; const int* d2_ = (const int*)d_in[7];
  const int* s3 = (const int*)d_in[8]; const int* d3_ = (const int*)d_in[9];
  const float* aeW = (const float*)d_in[10]; const float* aeB = (const float*)d_in[11];
  const float* teW = (const float*)d_in[12]; const float* teB = (const float*)d_in[13];
  const float* convW    = (const float*)d_in[14];
  const float* convAsrc = (const float*)d_in[15];
  const float* convAdst = (const float*)d_in[16];
  const float* convBias = (const float*)d_in[17];
  const float* bnG = (const float*)d_in[18]; const float* bnB = (const float*)d_in[19];
  const float* aW1 = (const float*)d_in[20]; const float* ab1 = (const float*)d_in[21];
  const float* ag  = (const float*)d_in[22]; const float* abe = (const float*)d_in[23];
  const float* aW2 = (const float*)d_in[24]; const float* ab2 = (const float*)d_in[25];
  const float* cW1 = (const float*)d_in[26]; const float* cb1 = (const float*)d_in[27];
  const float* cg1 = (const float*)d_in[28]; const float* cbe1 = (const float*)d_in[29];
  const float* cW2 = (const float*)d_in[30]; const float* cb2 = (const float*)d_in[31];
  const float* cg2 = (const float*)d_in[32]; const float* cbe2 = (const float*)d_in[33];
  const float* cW3 = (const float*)d_in[34]; const float* cb3 = (const float*)d_in[35];
  const float* cW4 = (const float*)d_in[36]; const float* cb4 = (const float*)d_in[37];
  float* ws = (float*)d_ws;
  int* wsi = (int*)d_ws;
  float* out = (float*)d_out;

  hipMemsetAsync(wsi + ROWP_I, 0, (size_t)240128 * sizeof(int), stream);
  hipMemsetAsync(ws + CST, 0, (size_t)384 * sizeof(float), stream);

  k_encoder<<<dim3(NTr, 2), 64, 0, stream>>>(x_agent, x_track, aeW, aeB, teW, teB, ws);

  k_hist<<<dim3(586, 4), 256, 0, stream>>>(d0_, d1_, d2_, d3_, wsi);
  k_scan<<<dim3(4), 256, 0, stream>>>(wsi);
  k_fill<<<dim3(586, 4), 256, 0, stream>>>(s0,d0_,s1,d1_,s2,d2_,s3,d3_, wsi);

  for (int l = 0; l < 3; ++l) {
    hipMemsetAsync(ws + BNST, 0, (size_t)256 * sizeof(float), stream);
    k_ald<<<dim3(469, 4), 256, 0, stream>>>(convW, convAdst, ws, l);
    k_h_als<<<dim3(1875, 4), 256, 0, stream>>>(convW, convAsrc, ws, l);
    k_agg<<<dim3(7500, 2), 256, 0, stream>>>(convBias, ws, l);
    k_bnnorm<<<dim3(7500, 2), 256, 0, stream>>>(bnG, bnB, ws, l);
  }

  k_criticstats<<<dim3(128, 2), 256, 0, stream>>>(ws);
  k_actor<<<dim3(3750, 2), 256, 0, stream>>>(aW1, ab1, ag, abe, aW2, ab2, ws, out);
  k_critic<<<1, 128, 0, stream>>>(cW1,cb1,cg1,cbe1,cW2,cb2,cg2,cbe2,cW3,cb3,cW4,cb4, ws, out);
}

// Round 6
// 1190.104 us; speedup vs baseline: 1.4197x; 1.0259x over previous
//
#include <hip/hip_runtime.h>
#include <math.h>

#define NAg 8000
#define NTr 30000
#define NE  150000

// ---- workspace layout (float offsets) ----
#define XA_OFF 0          // 8000*64
#define XT_OFF 512000     // 30000*64
#define H0_OFF 2432000    // bf16 interleaved [node][c*4+h], 256 ushorts/node
#define H1_OFF 4480000
#define H2_OFF 12160000
#define H3_OFF 14208000
#define ALS0 21888000
#define ALS1 21920000
#define ALS2 22040000
#define ALS3 22072000
#define ALD0 22192000
#define ALD1 22312000
#define ALD2 22344000
#define ALD3 22464000
#define ESRC_I 22496000   // int offsets into (int*)ws; 4 x 150000 = 600000 ints
#define OAACC 23104000    // 8000*64
#define OTACC 23616000    // 30000*64
#define BNST 25536000     // [type: 0 agent,1 track][2][64]
#define CST  25536256     // [type][3][64] (sum,sumsq,max-mapped)
#define ROWP_I 25536640   // 4 x 30016 ints (row_ptr per relation)
#define CURS_I 25656704   // 4 x 30016 ints (cursors)
#define RELSTRIDE 30016

typedef unsigned short ushortT;

__device__ __forceinline__ float lrelu(float x){ return x >= 0.f ? x : 0.2f*x; }
__device__ __forceinline__ unsigned fmap(float f){ unsigned u=__float_as_uint(f); return (u&0x80000000u)? ~u : (u|0x80000000u); }
__device__ __forceinline__ float funmap(unsigned u){ return (u&0x80000000u)? __uint_as_float(u&0x7FFFFFFFu) : __uint_as_float(~u); }
__device__ __forceinline__ float softplusf(float x){ return fmaxf(x,0.f) + log1pf(expf(-fabsf(x))); }
__device__ __forceinline__ ushortT f2bf(float f){
  unsigned u = __float_as_uint(f);
  unsigned r = u + 0x7FFFu + ((u>>16)&1u);   // RNE
  return (ushortT)(r>>16);
}
__device__ __forceinline__ float bf2f(ushortT s){ return __uint_as_float(((unsigned)s)<<16); }
__device__ __forceinline__ float wred64(float v){
  #pragma unroll
  for (int o=32;o;o>>=1) v += __shfl_xor(v,o);
  return v;
}
__device__ __forceinline__ float wred32(float v){
  #pragma unroll
  for (int o=16;o;o>>=1) v += __shfl_xor(v,o,32);
  return v;
}
__device__ __forceinline__ int selH(int r){ return r==0?H0_OFF: r==1?H1_OFF: r==2?H2_OFF:H3_OFF; }
__device__ __forceinline__ int selALS(int r){ return r==0?ALS0: r==1?ALS1: r==2?ALS2:ALS3; }
__device__ __forceinline__ int selALD(int r){ return r==0?ALD0: r==1?ALD1: r==2?ALD2:ALD3; }

// ---------------- encoder: x = relu(X @ W + b) ----------------
__global__ __launch_bounds__(64) void k_encoder(const float* xA, const float* xT,
    const float* aeW, const float* aeB, const float* teW, const float* teB, float* ws) {
  int type = blockIdx.y;
  int n = blockIdx.x;
  int N = type ? NTr : NAg;
  if (n >= N) return;
  int F = type ? 48 : 32;
  const float* X = type ? xT : xA;
  const float* W = type ? teW : aeW;
  const float* B = type ? teB : aeB;
  float* out = ws + (type ? XT_OFF : XA_OFF);
  __shared__ float xs[48];
  int t = threadIdx.x;
  if (t < F) xs[t] = X[n*F + t];
  __syncthreads();
  float acc = B[t];
  for (int k = 0; k < F; ++k) acc += xs[k] * W[k*64 + t];
  out[n*64 + t] = fmaxf(acc, 0.f);
}

// ---------------- CSR build: histogram ----------------
__global__ __launch_bounds__(256) void k_hist(const int* d0_,const int* d1_,const int* d2_,const int* d3_,
                                              int* wsi) {
  int r = blockIdx.y;
  const int* dp = r==0? d0_ : r==1? d1_ : r==2? d2_ : d3_;
  int e = blockIdx.x*256 + threadIdx.x;
  if (e >= NE) return;
  atomicAdd(&wsi[ROWP_I + r*RELSTRIDE + dp[e]], 1);
}

// ---------------- CSR build: exclusive scan per relation ----------------
__global__ __launch_bounds__(256) void k_scan(int* wsi) {
  int r = blockIdx.x;
  int n = ((r & 1) ? NAg : NTr) + 1;
  int* rp = wsi + ROWP_I + r*RELSTRIDE;
  __shared__ int part[256];
  int t = threadIdx.x;
  int chunk = (n + 255) / 256;
  int lo = t*chunk, hi = min(lo + chunk, n);
  int s = 0;
  for (int i = lo; i < hi; ++i) s += rp[i];
  part[t] = s;
  __syncthreads();
  if (t == 0) {
    int run = 0;
    for (int i = 0; i < 256; ++i) { int tm = part[i]; part[i] = run; run += tm; }
  }
  __syncthreads();
  int run = part[t];
  for (int i = lo; i < hi; ++i) { int tm = rp[i]; rp[i] = run; run += tm; }
}

// ---------------- CSR build: fill sorted src lists ----------------
__global__ __launch_bounds__(256) void k_fill(const int* s0,const int* d0_,const int* s1,const int* d1_,
    const int* s2,const int* d2_,const int* s3,const int* d3_, int* wsi) {
  int r = blockIdx.y;
  const int* sp = r==0? s0 : r==1? s1 : r==2? s2 : s3;
  const int* dp = r==0? d0_ : r==1? d1_ : r==2? d2_ : d3_;
  int e = blockIdx.x*256 + threadIdx.x;
  if (e >= NE) return;
  int d = dp[e];
  int pos = wsi[ROWP_I + r*RELSTRIDE + d] + atomicAdd(&wsi[CURS_I + r*RELSTRIDE + d], 1);
  wsi[ESRC_I + r*NE + pos] = sp[e];
}

// ---------------- al_d[n,h] = x_dst[n,:] . (W @ a_dst[h]) ----------------
__global__ __launch_bounds__(256) void k_ald(const float* convW, const float* convAdst,
                                             float* ws, int layer) {
  int r = blockIdx.y;
  int Nd = (r & 1) ? NAg : NTr;
  const float* W  = convW + (size_t)(layer*4 + r)*64*256;
  const float* ad = convAdst + (size_t)(layer*4 + r)*256;
  __shared__ float Wad[64*4];
  int t = threadIdx.x;
  {
    int k = t >> 2, h = t & 3;
    float s = 0.f;
    for (int c = 0; c < 64; ++c) s += W[k*256 + h*64 + c] * ad[h*64 + c];
    Wad[k*4 + h] = s;
  }
  __syncthreads();
  const float* xd = ws + ((r & 1) ? XA_OFF : XT_OFF);
  float* ald = ws + selALD(r);
  int n = blockIdx.x * 64 + (t >> 2);
  if (n >= Nd) return;
  int h = t & 3;
  float s = 0.f;
  for (int k = 0; k < 64; ++k) s += xd[n*64 + k] * Wad[k*4 + h];
  ald[n*4 + h] = s;
}

// ---------------- h = x_src @ W  (bf16 interleaved store)  +  al_s ----------------
__global__ __launch_bounds__(256) void k_h_als(const float* convW, const float* convAsrc,
                                               float* ws, int layer) {
  int r = blockIdx.y;
  int Ns = (r & 1) ? NTr : NAg;
  int row0 = blockIdx.x * 16;
  if (row0 >= Ns) return;
  const float* W  = convW + (size_t)(layer*4 + r)*64*256;
  const float* as = convAsrc + (size_t)(layer*4 + r)*256;
  const float* xg = ws + ((r & 1) ? XT_OFF : XA_OFF);
  ushortT* h16 = (ushortT*)(ws + selH(r));
  float* als = ws + selALS(r);
  __shared__ float xs[16][64];
  __shared__ float asl[256];
  int t = threadIdx.x;
  asl[t] = as[t];
  #pragma unroll
  for (int i = 0; i < 4; ++i) {
    int lin = i*256 + t;
    xs[lin>>6][lin&63] = xg[(row0 + (lin>>6))*64 + (lin&63)];
  }
  __syncthreads();
  int c0 = t & 63;
  int tr = t >> 6;
  float acc[4][4];
  #pragma unroll
  for (int i=0;i<4;i++){ acc[i][0]=0;acc[i][1]=0;acc[i][2]=0;acc[i][3]=0; }
  const float* Wc = W + c0;
  for (int k4 = 0; k4 < 16; ++k4) {
    float4 xv[4];
    #pragma unroll
    for (int i = 0; i < 4; ++i) xv[i] = *(const float4*)&xs[tr*4+i][k4*4];
    #pragma unroll
    for (int kk = 0; kk < 4; ++kk) {
      int k = k4*4 + kk;
      float w0 = Wc[k*256], w1 = Wc[k*256+64], w2 = Wc[k*256+128], w3 = Wc[k*256+192];
      #pragma unroll
      for (int i = 0; i < 4; ++i) {
        float x = (kk==0)?xv[i].x:(kk==1)?xv[i].y:(kk==2)?xv[i].z:xv[i].w;
        acc[i][0] += x*w0; acc[i][1] += x*w1; acc[i][2] += x*w2; acc[i][3] += x*w3;
      }
    }
  }
  #pragma unroll
  for (int i = 0; i < 4; ++i) {
    int row = row0 + tr*4 + i;
    ushort4 pk;
    pk.x = f2bf(acc[i][0]); pk.y = f2bf(acc[i][1]);
    pk.z = f2bf(acc[i][2]); pk.w = f2bf(acc[i][3]);
    *(ushort4*)(h16 + (size_t)row*256 + c0*4) = pk;
  }
  #pragma unroll
  for (int i = 0; i < 4; ++i) {
    #pragma unroll
    for (int j = 0; j < 4; ++j) {
      float v = acc[i][j] * asl[j*64 + c0];
      v = wred64(v);
      if (c0 == 0) als[(row0 + tr*4 + i)*4 + j] = v;
    }
  }
}

// ---------------- fused CSR aggregation (bf16 interleaved h, 4-edge unroll) ----------------
__global__ __launch_bounds__(256) void k_agg(const float* convBias, float* ws, int layer) {
  int type = blockIdx.y;                  // 0: track dst (rels 0,2), 1: agent dst (rels 1,3)
  int N = type ? NAg : NTr;
  if (blockIdx.x * 4 >= N) return;
  int t = threadIdx.x, lane = t & 63, hh = lane & 3, base = lane & ~3;
  int node = blockIdx.x*4 + (t >> 6);
  const int* wsi = (const int*)ws;
  float outv = 0.f;
  #pragma unroll
  for (int rr = 0; rr < 2; ++rr) {
    int r = type ? (rr ? 3 : 1) : (rr ? 2 : 0);
    const int* rp = wsi + ROWP_I + r*RELSTRIDE;
    const int* es = wsi + ESRC_I + r*NE;
    const float* als = ws + selALS(r);
    const ushortT* h16 = (const ushortT*)(ws + selH(r));
    float ad = (ws + selALD(r))[node*4 + hh];
    int p = rp[node], p1 = rp[node+1];
    float num0=0.f, num1=0.f, num2=0.f, num3=0.f, den=0.f;
    for (; p + 4 <= p1; p += 4) {
      int sa = es[p], sb = es[p+1], sc = es[p+2], sd4 = es[p+3];
      ushort4 va = *(const ushort4*)(h16 + (size_t)sa*256 + lane*4);
      ushort4 vb = *(const ushort4*)(h16 + (size_t)sb*256 + lane*4);
      ushort4 vc = *(const ushort4*)(h16 + (size_t)sc*256 + lane*4);
      ushort4 vd = *(const ushort4*)(h16 + (size_t)sd4*256 + lane*4);
      float la = als[sa*4+hh], lb = als[sb*4+hh], lc = als[sc*4+hh], ld = als[sd4*4+hh];
      float ea = __expf(lrelu(la + ad));
      float eb = __expf(lrelu(lb + ad));
      float ec = __expf(lrelu(lc + ad));
      float ed = __expf(lrelu(ld + ad));
      den += (ea+eb)+(ec+ed);
      float qa0=__shfl(ea,base), qa1=__shfl(ea,base+1), qa2=__shfl(ea,base+2), qa3=__shfl(ea,base+3);
      float qb0=__shfl(eb,base), qb1=__shfl(eb,base+1), qb2=__shfl(eb,base+2), qb3=__shfl(eb,base+3);
      float qc0=__shfl(ec,base), qc1=__shfl(ec,base+1), qc2=__shfl(ec,base+2), qc3=__shfl(ec,base+3);
      float qd0=__shfl(ed,base), qd1=__shfl(ed,base+1), qd2=__shfl(ed,base+2), qd3=__shfl(ed,base+3);
      num0 += qa0*bf2f(va.x) + qb0*bf2f(vb.x) + qc0*bf2f(vc.x) + qd0*bf2f(vd.x);
      num1 += qa1*bf2f(va.y) + qb1*bf2f(vb.y) + qc1*bf2f(vc.y) + qd1*bf2f(vd.y);
      num2 += qa2*bf2f(va.z) + qb2*bf2f(vb.z) + qc2*bf2f(vc.z) + qd2*bf2f(vd.z);
      num3 += qa3*bf2f(va.w) + qb3*bf2f(vb.w) + qc3*bf2f(vc.w) + qd3*bf2f(vd.w);
    }
    for (; p < p1; ++p) {
      int s = es[p];
      ushort4 va = *(const ushort4*)(h16 + (size_t)s*256 + lane*4);
      float e = __expf(lrelu(als[s*4 + hh] + ad));
      den += e;
      float q0 = __shfl(e, base), q1 = __shfl(e, base+1), q2 = __shfl(e, base+2), q3 = __shfl(e, base+3);
      num0 += q0*bf2f(va.x); num1 += q1*bf2f(va.y); num2 += q2*bf2f(va.z); num3 += q3*bf2f(va.w);
    }
    float rd = 1.f/(den + 1e-16f);        // lane hh holds den for head hh
    float r0 = __shfl(rd, base), r1 = __shfl(rd, base+1), r2 = __shfl(rd, base+2), r3 = __shfl(rd, base+3);
    outv += num0*r0 + num1*r1 + num2*r2 + num3*r3;
  }
  int rA = type ? 1 : 0, rB = type ? 3 : 2;
  float bavg = 0.5f*(convBias[(layer*4 + rA)*64 + lane] + convBias[(layer*4 + rB)*64 + lane]);
  float z = fmaxf(outv*0.125f + bavg, 0.f);
  float* acc = ws + (type ? OAACC : OTACC);
  acc[(size_t)node*64 + lane] = z;
  __shared__ float sdm[2][256];
  sdm[0][t] = z; sdm[1][t] = z*z;
  __syncthreads();
  if (t < 64) {
    float s1 = sdm[0][t] + sdm[0][t+64] + sdm[0][t+128] + sdm[0][t+192];
    float s2 = sdm[1][t] + sdm[1][t+64] + sdm[1][t+128] + sdm[1][t+192];
    int bt = type ? 0 : 1;
    atomicAdd(&ws[BNST + bt*128 + t], s1);
    atomicAdd(&ws[BNST + bt*128 + 64 + t], s2);
  }
}

// ---------------- batchnorm + residual, writes xa/xt in place ----------------
__global__ __launch_bounds__(256) void k_bnnorm(const float* bnG, const float* bnB, float* ws, int layer) {
  int type = blockIdx.y;                  // 0 agent, 1 track
  int N = type ? NTr : NAg;
  float* acc = ws + (type ? OTACC : OAACC);
  float* x = ws + (type ? XT_OFF : XA_OFF);
  int i = blockIdx.x*256 + threadIdx.x;
  if (i >= N*64) return;
  int c = i & 63;
  float Nf = (float)N;
  float s1 = ws[BNST + type*128 + c], s2 = ws[BNST + type*128 + 64 + c];
  float mu = s1/Nf, var = s2/Nf - mu*mu;
  float g = bnG[(layer*2 + type)*64 + c], b = bnB[(layer*2 + type)*64 + c];
  float y = g*(acc[i]-mu)*rsqrtf(var + 1e-5f) + b;
  if (layer > 0) y += x[i];
  x[i] = y;
}

// ---------------- actor heads ----------------
__global__ __launch_bounds__(256) void k_actor(const float* aW1, const float* ab1, const float* ag,
    const float* abe, const float* aW2, const float* ab2, const float* ws, float* out) {
  int type = blockIdx.y;
  int N = type ? NTr : NAg;
  int grp = threadIdx.x >> 5, j = threadIdx.x & 31;
  int n = blockIdx.x*8 + grp;
  if (n >= N) return;
  const float* x = ws + (type ? XT_OFF : XA_OFF) + (size_t)n*64;
  int iA = type ? 2 : 0;
  float vals[2];
  #pragma unroll
  for (int p = 0; p < 2; ++p) {
    int i = iA + p;
    float tv = ab1[i*32 + j];
    for (int k = 0; k < 64; ++k) tv += x[k] * aW1[i*2048 + k*32 + j];
    float mu = wred32(tv) * (1.f/32.f);
    float dz = tv - mu;
    float var = wred32(dz*dz) * (1.f/32.f);
    float hn = fmaxf(ag[i*32+j]*dz*rsqrtf(var + 1e-5f) + abe[i*32+j], 0.f);
    float s = wred32(hn * aW2[i*32 + j]) + ab2[i];
    vals[p] = softplusf(s) + 1.f;
  }
  if (j == 0) {
    int offA = type ? 24000 : 0, offB = type ? 54000 : 8000, offC = type ? 84000 : 16000;
    out[offA + n] = vals[0];
    out[offB + n] = vals[1];
    out[offC + n] = vals[0] / (vals[0] + vals[1]);
  }
}

// ---------------- critic column stats ----------------
__global__ __launch_bounds__(256) void k_criticstats(float* ws) {
  int type = blockIdx.y;
  int N = type ? NTr : NAg;
  const float* x = ws + (type ? XT_OFF : XA_OFF);
  int t = threadIdx.x;
  int c = t & 63;
  float s1 = 0.f, s2 = 0.f, mx = -3.4e38f;
  for (int n = blockIdx.x*4 + (t>>6); n < N; n += gridDim.x*4) {
    float v = x[(size_t)n*64 + c];
    s1 += v; s2 += v*v; mx = fmaxf(mx, v);
  }
  __shared__ float sd[3][256];
  sd[0][t]=s1; sd[1][t]=s2; sd[2][t]=mx;
  __syncthreads();
  if (t < 64) {
    s1 = sd[0][t]+sd[0][t+64]+sd[0][t+128]+sd[0][t+192];
    s2 = sd[1][t]+sd[1][t+64]+sd[1][t+128]+sd[1][t+192];
    mx = fmaxf(fmaxf(sd[2][t],sd[2][t+64]), fmaxf(sd[2][t+128],sd[2][t+192]));
    atomicAdd(&ws[CST + type*192 + c], s1);
    atomicAdd(&ws[CST + type*192 + 64 + c], s2);
    atomicMax((unsigned*)&ws[CST + type*192 + 128 + c], fmap(mx));
  }
}

__device__ __forceinline__ float blocksum128(float v, float* red) {
  int t = threadIdx.x;
  red[t] = v; __syncthreads();
  #pragma unroll
  for (int s = 64; s > 0; s >>= 1) { if (t < s) red[t] += red[t+s]; __syncthreads(); }
  float r = red[0]; __syncthreads();
  return r;
}

// ---------------- critic MLP ----------------
__global__ __launch_bounds__(128) void k_critic(const float* cW1,const float* cb1,const float* cg1,const float* cbe1,
    const float* cW2,const float* cb2,const float* cg2,const float* cbe2,
    const float* cW3,const float* cb3,const float* cW4,const float* cb4,
    const float* ws, float* out) {
  __shared__ float g[384];
  __shared__ float h1[128];
  __shared__ float h2s[64];
  __shared__ float red[128];
  int t = threadIdx.x;
  if (t < 64) {
    #pragma unroll
    for (int type = 0; type < 2; ++type) {
      float Nf = type ? 30000.f : 8000.f;
      float s1 = ws[CST + type*192 + t];
      float s2 = ws[CST + type*192 + 64 + t];
      unsigned mu_ = __float_as_uint(ws[CST + type*192 + 128 + t]);
      float mean = s1 / Nf;
      float sd = sqrtf(fmaxf((s2 - Nf*mean*mean) / (Nf - 1.f), 0.f));
      g[type*192 + t] = mean;
      g[type*192 + 64 + t] = funmap(mu_);
      g[type*192 + 128 + t] = sd;
    }
  }
  __syncthreads();
  float v = cb1[t];
  for (int k = 0; k < 384; ++k) v += g[k] * cW1[k*128 + t];
  float mu = blocksum128(v, red) * (1.f/128.f);
  float d = v - mu;
  float var = blocksum128(d*d, red) * (1.f/128.f);
  h1[t] = fmaxf(cg1[t]*d*rsqrtf(var + 1e-5f) + cbe1[t], 0.f);
  __syncthreads();
  float v2 = 0.f;
  if (t < 64) { v2 = cb2[t]; for (int k = 0; k < 128; ++k) v2 += h1[k] * cW2[k*64 + t]; }
  float mu2 = blocksum128(t < 64 ? v2 : 0.f, red) * (1.f/64.f);
  float d2 = v2 - mu2;
  float var2 = blocksum128(t < 64 ? d2*d2 : 0.f, red) * (1.f/64.f);
  if (t < 64) h2s[t] = fmaxf(cg2[t]*d2*rsqrtf(var2 + 1e-5f) + cbe2[t], 0.f);
  __syncthreads();
  float v3 = 0.f;
  if (t < 32) {
    v3 = cb3[t];
    for (int k = 0; k < 64; ++k) v3 += h2s[k] * cW3[k*32 + t];
    v3 = fmaxf(v3, 0.f);
  }
  float s4 = blocksum128(t < 32 ? v3 * cW4[t] : 0.f, red);
  if (t == 0) out[114000] = s4 + cb4[0];
}

extern "C" void kernel_launch(void* const* d_in, const int* in_sizes, int n_in,
                              void* d_out, int out_size, void* d_ws, size_t ws_size,
                              hipStream_t stream) {
  const float* x_agent = (const float*)d_in[0];
  const float* x_track = (const float*)d_in[1];
  const int* s0 = (const int*)d_in[2]; const int* d0_ = (const int*)d_in[3];
  const int* s1 = (const int*)d_in[4]; const int* d1_ = (const int*)d_in[5];
  const int* s2 = (const int*)d_in[6]; const int* d2_ = (const int*)d_in[7];
  const int* s3 = (const int*)d_in[8]; const int* d3_ = (const int*)d_in[9];
  const float* aeW = (const float*)d_in[10]; const float* aeB = (const float*)d_in[11];
  const float* teW = (const float*)d_in[12]; const float* teB = (const float*)d_in[13];
  const float* convW    = (const float*)d_in[14];
  const float* convAsrc = (const float*)d_in[15];
  const float* convAdst = (const float*)d_in[16];
  const float* convBias = (const float*)d_in[17];
  const float* bnG = (const float*)d_in[18]; const float* bnB = (const float*)d_in[19];
  const float* aW1 = (const float*)d_in[20]; const float* ab1 = (const float*)d_in[21];
  const float* ag  = (const float*)d_in[22]; const float* abe = (const float*)d_in[23];
  const float* aW2 = (const float*)d_in[24]; const float* ab2 = (const float*)d_in[25];
  const float* cW1 = (const float*)d_in[26]; const float* cb1 = (const float*)d_in[27];
  const float* cg1 = (const float*)d_in[28]; const float* cbe1 = (const float*)d_in[29];
  const float* cW2 = (const float*)d_in[30]; const float* cb2 = (const float*)d_in[31];
  const float* cg2 = (const float*)d_in[32]; const float* cbe2 = (const float*)d_in[33];
  const float* cW3 = (const float*)d_in[34]; const float* cb3 = (const float*)d_in[35];
  const float* cW4 = (const float*)d_in[36]; const float* cb4 = (const float*)d_in[37];
  float* ws = (float*)d_ws;
  int* wsi = (int*)d_ws;
  float* out = (float*)d_out;

  hipMemsetAsync(wsi + ROWP_I, 0, (size_t)240128 * sizeof(int), stream);
  hipMemsetAsync(ws + CST, 0, (size_t)384 * sizeof(float), stream);

  k_encoder<<<dim3(NTr, 2), 64, 0, stream>>>(x_agent, x_track, aeW, aeB, teW, teB, ws);

  k_hist<<<dim3(586, 4), 256, 0, stream>>>(d0_, d1_, d2_, d3_, wsi);
  k_scan<<<dim3(4), 256, 0, stream>>>(wsi);
  k_fill<<<dim3(586, 4), 256, 0, stream>>>(s0,d0_,s1,d1_,s2,d2_,s3,d3_, wsi);

  for (int l = 0; l < 3; ++l) {
    hipMemsetAsync(ws + BNST, 0, (size_t)256 * sizeof(float), stream);
    k_ald<<<dim3(469, 4), 256, 0, stream>>>(convW, convAdst, ws, l);
    k_h_als<<<dim3(1875, 4), 256, 0, stream>>>(convW, convAsrc, ws, l);
    k_agg<<<dim3(7500, 2), 256, 0, stream>>>(convBias, ws, l);
    k_bnnorm<<<dim3(7500, 2), 256, 0, stream>>>(bnG, bnB, ws, l);
  }

  k_criticstats<<<dim3(128, 2), 256, 0, stream>>>(ws);
  k_actor<<<dim3(3750, 2), 256, 0, stream>>>(aW1, ab1, ag, abe, aW2, ab2, ws, out);
  k_critic<<<1, 128, 0, stream>>>(cW1,cb1,cg1,cbe1,cW2,cb2,cg2,cbe2,cW3,cb3,cW4,cb4, ws, out);
}

// Round 7
// 723.400 us; speedup vs baseline: 2.3357x; 1.6452x over previous
//
#include <hip/hip_runtime.h>
#include <math.h>

#define NAg 8000
#define NTr 30000
#define NE  150000

// ---- workspace layout (float offsets) ----
#define XA_OFF 0          // 8000*64
#define XT_OFF 512000     // 30000*64
#define H0_OFF 2432000    // bf16 interleaved [node][c*4+h], 256 ushorts/node
#define H1_OFF 4480000    // (bf16 data ends at 8320000; free space after)
#define H2_OFF 12160000
#define H3_OFF 14208000
#define BNSTB 8320000     // 64 buckets x [2][128] = 16384 floats (in H1 slot free space)
#define ALS0 21888000
#define ALS1 21920000
#define ALS2 22040000
#define ALS3 22072000
#define ALD0 22192000
#define ALD1 22312000
#define ALD2 22344000
#define ALD3 22464000
#define ESRC_I 22496000   // int offsets into (int*)ws; 4 x 150000 = 600000 ints
#define OAACC 23104000    // 8000*64
#define OTACC 23616000    // 30000*64
#define BNST 25536000     // [type: 0 agent,1 track][2][64]
#define CST  25536256     // [type][3][64] (sum,sumsq,max-mapped)
#define ROWP_I 25536640   // 4 x 30016 ints (row_ptr per relation)
#define CURS_I 25656704   // 4 x 30016 ints (cursors)
#define RELSTRIDE 30016

typedef unsigned short ushortT;

__device__ __forceinline__ float lrelu(float x){ return x >= 0.f ? x : 0.2f*x; }
__device__ __forceinline__ unsigned fmap(float f){ unsigned u=__float_as_uint(f); return (u&0x80000000u)? ~u : (u|0x80000000u); }
__device__ __forceinline__ float funmap(unsigned u){ return (u&0x80000000u)? __uint_as_float(u&0x7FFFFFFFu) : __uint_as_float(~u); }
__device__ __forceinline__ float softplusf(float x){ return fmaxf(x,0.f) + log1pf(expf(-fabsf(x))); }
__device__ __forceinline__ ushortT f2bf(float f){
  unsigned u = __float_as_uint(f);
  unsigned r = u + 0x7FFFu + ((u>>16)&1u);   // RNE
  return (ushortT)(r>>16);
}
__device__ __forceinline__ float bf2f(ushortT s){ return __uint_as_float(((unsigned)s)<<16); }
__device__ __forceinline__ float wred64(float v){
  #pragma unroll
  for (int o=32;o;o>>=1) v += __shfl_xor(v,o);
  return v;
}
__device__ __forceinline__ float wred32(float v){
  #pragma unroll
  for (int o=16;o;o>>=1) v += __shfl_xor(v,o,32);
  return v;
}
__device__ __forceinline__ int selH(int r){ return r==0?H0_OFF: r==1?H1_OFF: r==2?H2_OFF:H3_OFF; }
__device__ __forceinline__ int selALS(int r){ return r==0?ALS0: r==1?ALS1: r==2?ALS2:ALS3; }
__device__ __forceinline__ int selALD(int r){ return r==0?ALD0: r==1?ALD1: r==2?ALD2:ALD3; }

// ---------------- encoder: x = relu(X @ W + b) ----------------
__global__ __launch_bounds__(64) void k_encoder(const float* xA, const float* xT,
    const float* aeW, const float* aeB, const float* teW, const float* teB, float* ws) {
  int type = blockIdx.y;
  int n = blockIdx.x;
  int N = type ? NTr : NAg;
  if (n >= N) return;
  int F = type ? 48 : 32;
  const float* X = type ? xT : xA;
  const float* W = type ? teW : aeW;
  const float* B = type ? teB : aeB;
  float* out = ws + (type ? XT_OFF : XA_OFF);
  __shared__ float xs[48];
  int t = threadIdx.x;
  if (t < F) xs[t] = X[n*F + t];
  __syncthreads();
  float acc = B[t];
  for (int k = 0; k < F; ++k) acc += xs[k] * W[k*64 + t];
  out[n*64 + t] = fmaxf(acc, 0.f);
}

// ---------------- CSR build: histogram ----------------
__global__ __launch_bounds__(256) void k_hist(const int* d0_,const int* d1_,const int* d2_,const int* d3_,
                                              int* wsi) {
  int r = blockIdx.y;
  const int* dp = r==0? d0_ : r==1? d1_ : r==2? d2_ : d3_;
  int e = blockIdx.x*256 + threadIdx.x;
  if (e >= NE) return;
  atomicAdd(&wsi[ROWP_I + r*RELSTRIDE + dp[e]], 1);
}

// ---------------- CSR build: exclusive scan per relation ----------------
__global__ __launch_bounds__(256) void k_scan(int* wsi) {
  int r = blockIdx.x;
  int n = ((r & 1) ? NAg : NTr) + 1;
  int* rp = wsi + ROWP_I + r*RELSTRIDE;
  __shared__ int part[256];
  int t = threadIdx.x;
  int chunk = (n + 255) / 256;
  int lo = t*chunk, hi = min(lo + chunk, n);
  int s = 0;
  for (int i = lo; i < hi; ++i) s += rp[i];
  part[t] = s;
  __syncthreads();
  if (t == 0) {
    int run = 0;
    for (int i = 0; i < 256; ++i) { int tm = part[i]; part[i] = run; run += tm; }
  }
  __syncthreads();
  int run = part[t];
  for (int i = lo; i < hi; ++i) { int tm = rp[i]; rp[i] = run; run += tm; }
}

// ---------------- CSR build: fill sorted src lists ----------------
__global__ __launch_bounds__(256) void k_fill(const int* s0,const int* d0_,const int* s1,const int* d1_,
    const int* s2,const int* d2_,const int* s3,const int* d3_, int* wsi) {
  int r = blockIdx.y;
  const int* sp = r==0? s0 : r==1? s1 : r==2? s2 : s3;
  const int* dp = r==0? d0_ : r==1? d1_ : r==2? d2_ : d3_;
  int e = blockIdx.x*256 + threadIdx.x;
  if (e >= NE) return;
  int d = dp[e];
  int pos = wsi[ROWP_I + r*RELSTRIDE + d] + atomicAdd(&wsi[CURS_I + r*RELSTRIDE + d], 1);
  wsi[ESRC_I + r*NE + pos] = sp[e];
}

// ---------------- al_d[n,h] = x_dst[n,:] . (W @ a_dst[h]) ----------------
__global__ __launch_bounds__(256) void k_ald(const float* convW, const float* convAdst,
                                             float* ws, int layer) {
  int r = blockIdx.y;
  int Nd = (r & 1) ? NAg : NTr;
  const float* W  = convW + (size_t)(layer*4 + r)*64*256;
  const float* ad = convAdst + (size_t)(layer*4 + r)*256;
  __shared__ float Wad[64*4];
  int t = threadIdx.x;
  {
    int k = t >> 2, h = t & 3;
    float s = 0.f;
    for (int c = 0; c < 64; ++c) s += W[k*256 + h*64 + c] * ad[h*64 + c];
    Wad[k*4 + h] = s;
  }
  __syncthreads();
  const float* xd = ws + ((r & 1) ? XA_OFF : XT_OFF);
  float* ald = ws + selALD(r);
  int n = blockIdx.x * 64 + (t >> 2);
  if (n >= Nd) return;
  int h = t & 3;
  float s = 0.f;
  for (int k = 0; k < 64; ++k) s += xd[n*64 + k] * Wad[k*4 + h];
  ald[n*4 + h] = s;
}

// ---------------- h = x_src @ W  (bf16 interleaved store)  +  al_s ----------------
__global__ __launch_bounds__(256) void k_h_als(const float* convW, const float* convAsrc,
                                               float* ws, int layer) {
  int r = blockIdx.y;
  int Ns = (r & 1) ? NTr : NAg;
  int row0 = blockIdx.x * 16;
  if (row0 >= Ns) return;
  const float* W  = convW + (size_t)(layer*4 + r)*64*256;
  const float* as = convAsrc + (size_t)(layer*4 + r)*256;
  const float* xg = ws + ((r & 1) ? XT_OFF : XA_OFF);
  ushortT* h16 = (ushortT*)(ws + selH(r));
  float* als = ws + selALS(r);
  __shared__ float xs[16][64];
  __shared__ float asl[256];
  int t = threadIdx.x;
  asl[t] = as[t];
  #pragma unroll
  for (int i = 0; i < 4; ++i) {
    int lin = i*256 + t;
    xs[lin>>6][lin&63] = xg[(row0 + (lin>>6))*64 + (lin&63)];
  }
  __syncthreads();
  int c0 = t & 63;
  int tr = t >> 6;
  float acc[4][4];
  #pragma unroll
  for (int i=0;i<4;i++){ acc[i][0]=0;acc[i][1]=0;acc[i][2]=0;acc[i][3]=0; }
  const float* Wc = W + c0;
  for (int k4 = 0; k4 < 16; ++k4) {
    float4 xv[4];
    #pragma unroll
    for (int i = 0; i < 4; ++i) xv[i] = *(const float4*)&xs[tr*4+i][k4*4];
    #pragma unroll
    for (int kk = 0; kk < 4; ++kk) {
      int k = k4*4 + kk;
      float w0 = Wc[k*256], w1 = Wc[k*256+64], w2 = Wc[k*256+128], w3 = Wc[k*256+192];
      #pragma unroll
      for (int i = 0; i < 4; ++i) {
        float x = (kk==0)?xv[i].x:(kk==1)?xv[i].y:(kk==2)?xv[i].z:xv[i].w;
        acc[i][0] += x*w0; acc[i][1] += x*w1; acc[i][2] += x*w2; acc[i][3] += x*w3;
      }
    }
  }
  #pragma unroll
  for (int i = 0; i < 4; ++i) {
    int row = row0 + tr*4 + i;
    ushort4 pk;
    pk.x = f2bf(acc[i][0]); pk.y = f2bf(acc[i][1]);
    pk.z = f2bf(acc[i][2]); pk.w = f2bf(acc[i][3]);
    *(ushort4*)(h16 + (size_t)row*256 + c0*4) = pk;
  }
  #pragma unroll
  for (int i = 0; i < 4; ++i) {
    #pragma unroll
    for (int j = 0; j < 4; ++j) {
      float v = acc[i][j] * asl[j*64 + c0];
      v = wred64(v);
      if (c0 == 0) als[(row0 + tr*4 + i)*4 + j] = v;
    }
  }
}

// ---------------- fused CSR aggregation (bf16 interleaved h, 4-edge unroll) ----------------
__global__ __launch_bounds__(256) void k_agg(const float* convBias, float* ws, int layer) {
  int type = blockIdx.y;                  // 0: track dst (rels 0,2), 1: agent dst (rels 1,3)
  int N = type ? NAg : NTr;
  if (blockIdx.x * 4 >= N) return;
  int t = threadIdx.x, lane = t & 63, hh = lane & 3, base = lane & ~3;
  int node = blockIdx.x*4 + (t >> 6);
  const int* wsi = (const int*)ws;
  float outv = 0.f;
  #pragma unroll
  for (int rr = 0; rr < 2; ++rr) {
    int r = type ? (rr ? 3 : 1) : (rr ? 2 : 0);
    const int* rp = wsi + ROWP_I + r*RELSTRIDE;
    const int* es = wsi + ESRC_I + r*NE;
    const float* als = ws + selALS(r);
    const ushortT* h16 = (const ushortT*)(ws + selH(r));
    float ad = (ws + selALD(r))[node*4 + hh];
    int p = rp[node], p1 = rp[node+1];
    float num0=0.f, num1=0.f, num2=0.f, num3=0.f, den=0.f;
    for (; p + 4 <= p1; p += 4) {
      int sa = es[p], sb = es[p+1], sc = es[p+2], sd4 = es[p+3];
      ushort4 va = *(const ushort4*)(h16 + (size_t)sa*256 + lane*4);
      ushort4 vb = *(const ushort4*)(h16 + (size_t)sb*256 + lane*4);
      ushort4 vc = *(const ushort4*)(h16 + (size_t)sc*256 + lane*4);
      ushort4 vd = *(const ushort4*)(h16 + (size_t)sd4*256 + lane*4);
      float la = als[sa*4+hh], lb = als[sb*4+hh], lc = als[sc*4+hh], ld = als[sd4*4+hh];
      float ea = __expf(lrelu(la + ad));
      float eb = __expf(lrelu(lb + ad));
      float ec = __expf(lrelu(lc + ad));
      float ed = __expf(lrelu(ld + ad));
      den += (ea+eb)+(ec+ed);
      float qa0=__shfl(ea,base), qa1=__shfl(ea,base+1), qa2=__shfl(ea,base+2), qa3=__shfl(ea,base+3);
      float qb0=__shfl(eb,base), qb1=__shfl(eb,base+1), qb2=__shfl(eb,base+2), qb3=__shfl(eb,base+3);
      float qc0=__shfl(ec,base), qc1=__shfl(ec,base+1), qc2=__shfl(ec,base+2), qc3=__shfl(ec,base+3);
      float qd0=__shfl(ed,base), qd1=__shfl(ed,base+1), qd2=__shfl(ed,base+2), qd3=__shfl(ed,base+3);
      num0 += qa0*bf2f(va.x) + qb0*bf2f(vb.x) + qc0*bf2f(vc.x) + qd0*bf2f(vd.x);
      num1 += qa1*bf2f(va.y) + qb1*bf2f(vb.y) + qc1*bf2f(vc.y) + qd1*bf2f(vd.y);
      num2 += qa2*bf2f(va.z) + qb2*bf2f(vb.z) + qc2*bf2f(vc.z) + qd2*bf2f(vd.z);
      num3 += qa3*bf2f(va.w) + qb3*bf2f(vb.w) + qc3*bf2f(vc.w) + qd3*bf2f(vd.w);
    }
    for (; p < p1; ++p) {
      int s = es[p];
      ushort4 va = *(const ushort4*)(h16 + (size_t)s*256 + lane*4);
      float e = __expf(lrelu(als[s*4 + hh] + ad));
      den += e;
      float q0 = __shfl(e, base), q1 = __shfl(e, base+1), q2 = __shfl(e, base+2), q3 = __shfl(e, base+3);
      num0 += q0*bf2f(va.x); num1 += q1*bf2f(va.y); num2 += q2*bf2f(va.z); num3 += q3*bf2f(va.w);
    }
    float rd = 1.f/(den + 1e-16f);        // lane hh holds den for head hh
    float r0 = __shfl(rd, base), r1 = __shfl(rd, base+1), r2 = __shfl(rd, base+2), r3 = __shfl(rd, base+3);
    outv += num0*r0 + num1*r1 + num2*r2 + num3*r3;
  }
  int rA = type ? 1 : 0, rB = type ? 3 : 2;
  float bavg = 0.5f*(convBias[(layer*4 + rA)*64 + lane] + convBias[(layer*4 + rB)*64 + lane]);
  float z = fmaxf(outv*0.125f + bavg, 0.f);
  float* acc = ws + (type ? OAACC : OTACC);
  acc[(size_t)node*64 + lane] = z;
  // BN column stats -> 64 spread buckets (avoids same-line atomic serialization)
  __shared__ float sdm[2][256];
  sdm[0][t] = z; sdm[1][t] = z*z;
  __syncthreads();
  if (t < 64) {
    float s1 = sdm[0][t] + sdm[0][t+64] + sdm[0][t+128] + sdm[0][t+192];
    float s2 = sdm[1][t] + sdm[1][t+64] + sdm[1][t+128] + sdm[1][t+192];
    int bt = type ? 0 : 1;
    int bucket = blockIdx.x & 63;
    atomicAdd(&ws[BNSTB + bucket*256 + bt*128 + t], s1);
    atomicAdd(&ws[BNSTB + bucket*256 + bt*128 + 64 + t], s2);
  }
}

// ---------------- reduce 64 BN-stat buckets -> BNST ----------------
__global__ __launch_bounds__(256) void k_bnred(float* ws) {
  int t = threadIdx.x;
  float s = 0.f;
  #pragma unroll
  for (int b = 0; b < 64; ++b) s += ws[BNSTB + b*256 + t];
  ws[BNST + t] = s;
}

// ---------------- batchnorm + residual, writes xa/xt in place ----------------
__global__ __launch_bounds__(256) void k_bnnorm(const float* bnG, const float* bnB, float* ws, int layer) {
  int type = blockIdx.y;                  // 0 agent, 1 track
  int N = type ? NTr : NAg;
  float* acc = ws + (type ? OTACC : OAACC);
  float* x = ws + (type ? XT_OFF : XA_OFF);
  int i = blockIdx.x*256 + threadIdx.x;
  if (i >= N*64) return;
  int c = i & 63;
  float Nf = (float)N;
  float s1 = ws[BNST + type*128 + c], s2 = ws[BNST + type*128 + 64 + c];
  float mu = s1/Nf, var = s2/Nf - mu*mu;
  float g = bnG[(layer*2 + type)*64 + c], b = bnB[(layer*2 + type)*64 + c];
  float y = g*(acc[i]-mu)*rsqrtf(var + 1e-5f) + b;
  if (layer > 0) y += x[i];
  x[i] = y;
}

// ---------------- actor heads ----------------
__global__ __launch_bounds__(256) void k_actor(const float* aW1, const float* ab1, const float* ag,
    const float* abe, const float* aW2, const float* ab2, const float* ws, float* out) {
  int type = blockIdx.y;
  int N = type ? NTr : NAg;
  int grp = threadIdx.x >> 5, j = threadIdx.x & 31;
  int n = blockIdx.x*8 + grp;
  if (n >= N) return;
  const float* x = ws + (type ? XT_OFF : XA_OFF) + (size_t)n*64;
  int iA = type ? 2 : 0;
  float vals[2];
  #pragma unroll
  for (int p = 0; p < 2; ++p) {
    int i = iA + p;
    float tv = ab1[i*32 + j];
    for (int k = 0; k < 64; ++k) tv += x[k] * aW1[i*2048 + k*32 + j];
    float mu = wred32(tv) * (1.f/32.f);
    float dz = tv - mu;
    float var = wred32(dz*dz) * (1.f/32.f);
    float hn = fmaxf(ag[i*32+j]*dz*rsqrtf(var + 1e-5f) + abe[i*32+j], 0.f);
    float s = wred32(hn * aW2[i*32 + j]) + ab2[i];
    vals[p] = softplusf(s) + 1.f;
  }
  if (j == 0) {
    int offA = type ? 24000 : 0, offB = type ? 54000 : 8000, offC = type ? 84000 : 16000;
    out[offA + n] = vals[0];
    out[offB + n] = vals[1];
    out[offC + n] = vals[0] / (vals[0] + vals[1]);
  }
}

// ---------------- critic column stats ----------------
__global__ __launch_bounds__(256) void k_criticstats(float* ws) {
  int type = blockIdx.y;
  int N = type ? NTr : NAg;
  const float* x = ws + (type ? XT_OFF : XA_OFF);
  int t = threadIdx.x;
  int c = t & 63;
  float s1 = 0.f, s2 = 0.f, mx = -3.4e38f;
  for (int n = blockIdx.x*4 + (t>>6); n < N; n += gridDim.x*4) {
    float v = x[(size_t)n*64 + c];
    s1 += v; s2 += v*v; mx = fmaxf(mx, v);
  }
  __shared__ float sd[3][256];
  sd[0][t]=s1; sd[1][t]=s2; sd[2][t]=mx;
  __syncthreads();
  if (t < 64) {
    s1 = sd[0][t]+sd[0][t+64]+sd[0][t+128]+sd[0][t+192];
    s2 = sd[1][t]+sd[1][t+64]+sd[1][t+128]+sd[1][t+192];
    mx = fmaxf(fmaxf(sd[2][t],sd[2][t+64]), fmaxf(sd[2][t+128],sd[2][t+192]));
    atomicAdd(&ws[CST + type*192 + c], s1);
    atomicAdd(&ws[CST + type*192 + 64 + c], s2);
    atomicMax((unsigned*)&ws[CST + type*192 + 128 + c], fmap(mx));
  }
}

__device__ __forceinline__ float blocksum128(float v, float* red) {
  int t = threadIdx.x;
  red[t] = v; __syncthreads();
  #pragma unroll
  for (int s = 64; s > 0; s >>= 1) { if (t < s) red[t] += red[t+s]; __syncthreads(); }
  float r = red[0]; __syncthreads();
  return r;
}

// ---------------- critic MLP ----------------
__global__ __launch_bounds__(128) void k_critic(const float* cW1,const float* cb1,const float* cg1,const float* cbe1,
    const float* cW2,const float* cb2,const float* cg2,const float* cbe2,
    const float* cW3,const float* cb3,const float* cW4,const float* cb4,
    const float* ws, float* out) {
  __shared__ float g[384];
  __shared__ float h1[128];
  __shared__ float h2s[64];
  __shared__ float red[128];
  int t = threadIdx.x;
  if (t < 64) {
    #pragma unroll
    for (int type = 0; type < 2; ++type) {
      float Nf = type ? 30000.f : 8000.f;
      float s1 = ws[CST + type*192 + t];
      float s2 = ws[CST + type*192 + 64 + t];
      unsigned mu_ = __float_as_uint(ws[CST + type*192 + 128 + t]);
      float mean = s1 / Nf;
      float sd = sqrtf(fmaxf((s2 - Nf*mean*mean) / (Nf - 1.f), 0.f));
      g[type*192 + t] = mean;
      g[type*192 + 64 + t] = funmap(mu_);
      g[type*192 + 128 + t] = sd;
    }
  }
  __syncthreads();
  float v = cb1[t];
  for (int k = 0; k < 384; ++k) v += g[k] * cW1[k*128 + t];
  float mu = blocksum128(v, red) * (1.f/128.f);
  float d = v - mu;
  float var = blocksum128(d*d, red) * (1.f/128.f);
  h1[t] = fmaxf(cg1[t]*d*rsqrtf(var + 1e-5f) + cbe1[t], 0.f);
  __syncthreads();
  float v2 = 0.f;
  if (t < 64) { v2 = cb2[t]; for (int k = 0; k < 128; ++k) v2 += h1[k] * cW2[k*64 + t]; }
  float mu2 = blocksum128(t < 64 ? v2 : 0.f, red) * (1.f/64.f);
  float d2 = v2 - mu2;
  float var2 = blocksum128(t < 64 ? d2*d2 : 0.f, red) * (1.f/64.f);
  if (t < 64) h2s[t] = fmaxf(cg2[t]*d2*rsqrtf(var2 + 1e-5f) + cbe2[t], 0.f);
  __syncthreads();
  float v3 = 0.f;
  if (t < 32) {
    v3 = cb3[t];
    for (int k = 0; k < 64; ++k) v3 += h2s[k] * cW3[k*32 + t];
    v3 = fmaxf(v3, 0.f);
  }
  float s4 = blocksum128(t < 32 ? v3 * cW4[t] : 0.f, red);
  if (t == 0) out[114000] = s4 + cb4[0];
}

extern "C" void kernel_launch(void* const* d_in, const int* in_sizes, int n_in,
                              void* d_out, int out_size, void* d_ws, size_t ws_size,
                              hipStream_t stream) {
  const float* x_agent = (const float*)d_in[0];
  const float* x_track = (const float*)d_in[1];
  const int* s0 = (const int*)d_in[2]; const int* d0_ = (const int*)d_in[3];
  const int* s1 = (const int*)d_in[4]; const int* d1_ = (const int*)d_in[5];
  const int* s2 = (const int*)d_in[6]; const int* d2_ = (const int*)d_in[7];
  const int* s3 = (const int*)d_in[8]; const int* d3_ = (const int*)d_in[9];
  const float* aeW = (const float*)d_in[10]; const float* aeB = (const float*)d_in[11];
  const float* teW = (const float*)d_in[12]; const float* teB = (const float*)d_in[13];
  const float* convW    = (const float*)d_in[14];
  const float* convAsrc = (const float*)d_in[15];
  const float* convAdst = (const float*)d_in[16];
  const float* convBias = (const float*)d_in[17];
  const float* bnG = (const float*)d_in[18]; const float* bnB = (const float*)d_in[19];
  const float* aW1 = (const float*)d_in[20]; const float* ab1 = (const float*)d_in[21];
  const float* ag  = (const float*)d_in[22]; const float* abe = (const float*)d_in[23];
  const float* aW2 = (const float*)d_in[24]; const float* ab2 = (const float*)d_in[25];
  const float* cW1 = (const float*)d_in[26]; const float* cb1 = (const float*)d_in[27];
  const float* cg1 = (const float*)d_in[28]; const float* cbe1 = (const float*)d_in[29];
  const float* cW2 = (const float*)d_in[30]; const float* cb2 = (const float*)d_in[31];
  const float* cg2 = (const float*)d_in[32]; const float* cbe2 = (const float*)d_in[33];
  const float* cW3 = (const float*)d_in[34]; const float* cb3 = (const float*)d_in[35];
  const float* cW4 = (const float*)d_in[36]; const float* cb4 = (const float*)d_in[37];
  float* ws = (float*)d_ws;
  int* wsi = (int*)d_ws;
  float* out = (float*)d_out;

  hipMemsetAsync(wsi + ROWP_I, 0, (size_t)240128 * sizeof(int), stream);
  hipMemsetAsync(ws + CST, 0, (size_t)384 * sizeof(float), stream);

  k_encoder<<<dim3(NTr, 2), 64, 0, stream>>>(x_agent, x_track, aeW, aeB, teW, teB, ws);

  k_hist<<<dim3(586, 4), 256, 0, stream>>>(d0_, d1_, d2_, d3_, wsi);
  k_scan<<<dim3(4), 256, 0, stream>>>(wsi);
  k_fill<<<dim3(586, 4), 256, 0, stream>>>(s0,d0_,s1,d1_,s2,d2_,s3,d3_, wsi);

  for (int l = 0; l < 3; ++l) {
    hipMemsetAsync(ws + BNSTB, 0, (size_t)16384 * sizeof(float), stream);
    k_ald<<<dim3(469, 4), 256, 0, stream>>>(convW, convAdst, ws, l);
    k_h_als<<<dim3(1875, 4), 256, 0, stream>>>(convW, convAsrc, ws, l);
    k_agg<<<dim3(7500, 2), 256, 0, stream>>>(convBias, ws, l);
    k_bnred<<<1, 256, 0, stream>>>(ws);
    k_bnnorm<<<dim3(7500, 2), 256, 0, stream>>>(bnG, bnB, ws, l);
  }

  k_criticstats<<<dim3(128, 2), 256, 0, stream>>>(ws);
  k_actor<<<dim3(3750, 2), 256, 0, stream>>>(aW1, ab1, ag, abe, aW2, ab2, ws, out);
  k_critic<<<1, 128, 0, stream>>>(cW1,cb1,cg1,cbe1,cW2,cb2,cg2,cbe2,cW3,cb3,cW4,cb4, ws, out);
}

// Round 8
// 677.147 us; speedup vs baseline: 2.4952x; 1.0683x over previous
//
#include <hip/hip_runtime.h>
#include <math.h>

#define NAg 8000
#define NTr 30000
#define NE  150000

// ---- workspace layout (float offsets) ----
#define XA_OFF 0          // 8000*64
#define XT_OFF 512000     // 30000*64
#define H0_OFF 2432000    // bf16 interleaved [node][c*4+h], 256 ushorts/node
#define H1_OFF 4480000    // (bf16 data ends at 8320000; free space after)
#define H2_OFF 12160000
#define H3_OFF 14208000
#define BNSTB 8320000     // 64 buckets x [2][128] = 16384 floats
#define ALS0 21888000
#define ALS1 21920000
#define ALS2 22040000
#define ALS3 22072000
#define ALD0 22192000
#define ALD1 22312000
#define ALD2 22344000
#define ALD3 22464000
#define ESRC_I 22496000   // int offsets into (int*)ws; 4 x 150000 = 600000 ints
#define OAACC 23104000    // 8000*64
#define OTACC 23616000    // 30000*64
#define BNST 25536000     // [type: 0 agent,1 track][2][64]
#define CST  25536256     // [type][3][64] (sum,sumsq,max-mapped)
#define ROWP_I 25536640   // 4 x 30016 ints (row_ptr per relation)
#define CURS_I 25656704   // 4 x 30016 ints (cursors)
#define RELSTRIDE 30016

typedef unsigned short ushortT;

__device__ __forceinline__ float lrelu(float x){ return x >= 0.f ? x : 0.2f*x; }
__device__ __forceinline__ unsigned fmap(float f){ unsigned u=__float_as_uint(f); return (u&0x80000000u)? ~u : (u|0x80000000u); }
__device__ __forceinline__ float funmap(unsigned u){ return (u&0x80000000u)? __uint_as_float(u&0x7FFFFFFFu) : __uint_as_float(~u); }
__device__ __forceinline__ float softplusf(float x){ return fmaxf(x,0.f) + log1pf(expf(-fabsf(x))); }
__device__ __forceinline__ ushortT f2bf(float f){
  unsigned u = __float_as_uint(f);
  unsigned r = u + 0x7FFFu + ((u>>16)&1u);   // RNE
  return (ushortT)(r>>16);
}
__device__ __forceinline__ float bf2f(ushortT s){ return __uint_as_float(((unsigned)s)<<16); }
__device__ __forceinline__ float wred64(float v){
  #pragma unroll
  for (int o=32;o;o>>=1) v += __shfl_xor(v,o);
  return v;
}
__device__ __forceinline__ float wred32(float v){
  #pragma unroll
  for (int o=16;o;o>>=1) v += __shfl_xor(v,o,32);
  return v;
}
__device__ __forceinline__ int selH(int r){ return r==0?H0_OFF: r==1?H1_OFF: r==2?H2_OFF:H3_OFF; }
__device__ __forceinline__ int selALS(int r){ return r==0?ALS0: r==1?ALS1: r==2?ALS2:ALS3; }
__device__ __forceinline__ int selALD(int r){ return r==0?ALD0: r==1?ALD1: r==2?ALD2:ALD3; }

// ---------------- encoder: x = relu(X @ W + b), 4 nodes/block ----------------
__global__ __launch_bounds__(256) void k_encoder(const float* xA, const float* xT,
    const float* aeW, const float* aeB, const float* teW, const float* teB, float* ws) {
  int type = blockIdx.y;
  int N = type ? NTr : NAg;
  int t = threadIdx.x, wv = t >> 6, lane = t & 63;
  int n = blockIdx.x*4 + wv;
  int F = type ? 48 : 32;
  const float* X = type ? xT : xA;
  const float* W = type ? teW : aeW;
  const float* B = type ? teB : aeB;
  float* out = ws + (type ? XT_OFF : XA_OFF);
  __shared__ float xs[4][48];
  if (n < N && lane < F) xs[wv][lane] = X[(size_t)n*F + lane];
  __syncthreads();
  if (n >= N) return;
  float acc = B[lane];
  for (int k = 0; k < F; ++k) acc += xs[wv][k] * W[k*64 + lane];
  out[(size_t)n*64 + lane] = fmaxf(acc, 0.f);
}

// ---------------- CSR build: histogram ----------------
__global__ __launch_bounds__(256) void k_hist(const int* d0_,const int* d1_,const int* d2_,const int* d3_,
                                              int* wsi) {
  int r = blockIdx.y;
  const int* dp = r==0? d0_ : r==1? d1_ : r==2? d2_ : d3_;
  int e = blockIdx.x*256 + threadIdx.x;
  if (e >= NE) return;
  atomicAdd(&wsi[ROWP_I + r*RELSTRIDE + dp[e]], 1);
}

// ---------------- CSR build: exclusive scan per relation ----------------
__global__ __launch_bounds__(256) void k_scan(int* wsi) {
  int r = blockIdx.x;
  int n = ((r & 1) ? NAg : NTr) + 1;
  int* rp = wsi + ROWP_I + r*RELSTRIDE;
  __shared__ int part[256];
  int t = threadIdx.x;
  int chunk = (n + 255) / 256;
  int lo = t*chunk, hi = min(lo + chunk, n);
  int s = 0;
  for (int i = lo; i < hi; ++i) s += rp[i];
  part[t] = s;
  __syncthreads();
  if (t == 0) {
    int run = 0;
    for (int i = 0; i < 256; ++i) { int tm = part[i]; part[i] = run; run += tm; }
  }
  __syncthreads();
  int run = part[t];
  for (int i = lo; i < hi; ++i) { int tm = rp[i]; rp[i] = run; run += tm; }
}

// ---------------- CSR build: fill sorted src lists ----------------
__global__ __launch_bounds__(256) void k_fill(const int* s0,const int* d0_,const int* s1,const int* d1_,
    const int* s2,const int* d2_,const int* s3,const int* d3_, int* wsi) {
  int r = blockIdx.y;
  const int* sp = r==0? s0 : r==1? s1 : r==2? s2 : s3;
  const int* dp = r==0? d0_ : r==1? d1_ : r==2? d2_ : d3_;
  int e = blockIdx.x*256 + threadIdx.x;
  if (e >= NE) return;
  int d = dp[e];
  int pos = wsi[ROWP_I + r*RELSTRIDE + d] + atomicAdd(&wsi[CURS_I + r*RELSTRIDE + d], 1);
  wsi[ESRC_I + r*NE + pos] = sp[e];
}

// ---------------- al_d[n,h] = x_dst[n,:] . (W @ a_dst[h]) ----------------
__global__ __launch_bounds__(256) void k_ald(const float* convW, const float* convAdst,
                                             float* ws, int layer) {
  int r = blockIdx.y;
  int Nd = (r & 1) ? NAg : NTr;
  const float* W  = convW + (size_t)(layer*4 + r)*64*256;
  const float* ad = convAdst + (size_t)(layer*4 + r)*256;
  __shared__ float Wad[64*4];
  int t = threadIdx.x;
  {
    int k = t >> 2, h = t & 3;
    float s = 0.f;
    for (int c = 0; c < 64; ++c) s += W[k*256 + h*64 + c] * ad[h*64 + c];
    Wad[k*4 + h] = s;
  }
  __syncthreads();
  const float* xd = ws + ((r & 1) ? XA_OFF : XT_OFF);
  float* ald = ws + selALD(r);
  int n = blockIdx.x * 64 + (t >> 2);
  if (n >= Nd) return;
  int h = t & 3;
  float s = 0.f;
  for (int k = 0; k < 64; ++k) s += xd[n*64 + k] * Wad[k*4 + h];
  ald[n*4 + h] = s;
}

// ---------------- h = x_src @ W  (bf16 interleaved store)  +  al_s ----------------
__global__ __launch_bounds__(256) void k_h_als(const float* convW, const float* convAsrc,
                                               float* ws, int layer) {
  int r = blockIdx.y;
  int Ns = (r & 1) ? NTr : NAg;
  int row0 = blockIdx.x * 16;
  if (row0 >= Ns) return;
  const float* W  = convW + (size_t)(layer*4 + r)*64*256;
  const float* as = convAsrc + (size_t)(layer*4 + r)*256;
  const float* xg = ws + ((r & 1) ? XT_OFF : XA_OFF);
  ushortT* h16 = (ushortT*)(ws + selH(r));
  float* als = ws + selALS(r);
  __shared__ float xs[16][64];
  __shared__ float asl[256];
  int t = threadIdx.x;
  asl[t] = as[t];
  #pragma unroll
  for (int i = 0; i < 4; ++i) {
    int lin = i*256 + t;
    xs[lin>>6][lin&63] = xg[(row0 + (lin>>6))*64 + (lin&63)];
  }
  __syncthreads();
  int c0 = t & 63;
  int tr = t >> 6;
  float acc[4][4];
  #pragma unroll
  for (int i=0;i<4;i++){ acc[i][0]=0;acc[i][1]=0;acc[i][2]=0;acc[i][3]=0; }
  const float* Wc = W + c0;
  for (int k4 = 0; k4 < 16; ++k4) {
    float4 xv[4];
    #pragma unroll
    for (int i = 0; i < 4; ++i) xv[i] = *(const float4*)&xs[tr*4+i][k4*4];
    #pragma unroll
    for (int kk = 0; kk < 4; ++kk) {
      int k = k4*4 + kk;
      float w0 = Wc[k*256], w1 = Wc[k*256+64], w2 = Wc[k*256+128], w3 = Wc[k*256+192];
      #pragma unroll
      for (int i = 0; i < 4; ++i) {
        float x = (kk==0)?xv[i].x:(kk==1)?xv[i].y:(kk==2)?xv[i].z:xv[i].w;
        acc[i][0] += x*w0; acc[i][1] += x*w1; acc[i][2] += x*w2; acc[i][3] += x*w3;
      }
    }
  }
  #pragma unroll
  for (int i = 0; i < 4; ++i) {
    int row = row0 + tr*4 + i;
    ushort4 pk;
    pk.x = f2bf(acc[i][0]); pk.y = f2bf(acc[i][1]);
    pk.z = f2bf(acc[i][2]); pk.w = f2bf(acc[i][3]);
    *(ushort4*)(h16 + (size_t)row*256 + c0*4) = pk;
  }
  #pragma unroll
  for (int i = 0; i < 4; ++i) {
    #pragma unroll
    for (int j = 0; j < 4; ++j) {
      float v = acc[i][j] * asl[j*64 + c0];
      v = wred64(v);
      if (c0 == 0) als[(row0 + tr*4 + i)*4 + j] = v;
    }
  }
}

// ---------------- fused CSR aggregation (bf16 interleaved h, 4-edge unroll) ----------------
__global__ __launch_bounds__(256) void k_agg(const float* convBias, float* ws, int layer) {
  int type = blockIdx.y;                  // 0: track dst (rels 0,2), 1: agent dst (rels 1,3)
  int N = type ? NAg : NTr;
  if (blockIdx.x * 4 >= N) return;
  int t = threadIdx.x, lane = t & 63, hh = lane & 3, base = lane & ~3;
  int node = blockIdx.x*4 + (t >> 6);
  const int* wsi = (const int*)ws;
  float outv = 0.f;
  #pragma unroll
  for (int rr = 0; rr < 2; ++rr) {
    int r = type ? (rr ? 3 : 1) : (rr ? 2 : 0);
    const int* rp = wsi + ROWP_I + r*RELSTRIDE;
    const int* es = wsi + ESRC_I + r*NE;
    const float* als = ws + selALS(r);
    const ushortT* h16 = (const ushortT*)(ws + selH(r));
    float ad = (ws + selALD(r))[node*4 + hh];
    int p = rp[node], p1 = rp[node+1];
    float num0=0.f, num1=0.f, num2=0.f, num3=0.f, den=0.f;
    for (; p + 4 <= p1; p += 4) {
      int sa = es[p], sb = es[p+1], sc = es[p+2], sd4 = es[p+3];
      ushort4 va = *(const ushort4*)(h16 + (size_t)sa*256 + lane*4);
      ushort4 vb = *(const ushort4*)(h16 + (size_t)sb*256 + lane*4);
      ushort4 vc = *(const ushort4*)(h16 + (size_t)sc*256 + lane*4);
      ushort4 vd = *(const ushort4*)(h16 + (size_t)sd4*256 + lane*4);
      float la = als[sa*4+hh], lb = als[sb*4+hh], lc = als[sc*4+hh], ld = als[sd4*4+hh];
      float ea = __expf(lrelu(la + ad));
      float eb = __expf(lrelu(lb + ad));
      float ec = __expf(lrelu(lc + ad));
      float ed = __expf(lrelu(ld + ad));
      den += (ea+eb)+(ec+ed);
      float qa0=__shfl(ea,base), qa1=__shfl(ea,base+1), qa2=__shfl(ea,base+2), qa3=__shfl(ea,base+3);
      float qb0=__shfl(eb,base), qb1=__shfl(eb,base+1), qb2=__shfl(eb,base+2), qb3=__shfl(eb,base+3);
      float qc0=__shfl(ec,base), qc1=__shfl(ec,base+1), qc2=__shfl(ec,base+2), qc3=__shfl(ec,base+3);
      float qd0=__shfl(ed,base), qd1=__shfl(ed,base+1), qd2=__shfl(ed,base+2), qd3=__shfl(ed,base+3);
      num0 += qa0*bf2f(va.x) + qb0*bf2f(vb.x) + qc0*bf2f(vc.x) + qd0*bf2f(vd.x);
      num1 += qa1*bf2f(va.y) + qb1*bf2f(vb.y) + qc1*bf2f(vc.y) + qd1*bf2f(vd.y);
      num2 += qa2*bf2f(va.z) + qb2*bf2f(vb.z) + qc2*bf2f(vc.z) + qd2*bf2f(vd.z);
      num3 += qa3*bf2f(va.w) + qb3*bf2f(vb.w) + qc3*bf2f(vc.w) + qd3*bf2f(vd.w);
    }
    for (; p < p1; ++p) {
      int s = es[p];
      ushort4 va = *(const ushort4*)(h16 + (size_t)s*256 + lane*4);
      float e = __expf(lrelu(als[s*4 + hh] + ad));
      den += e;
      float q0 = __shfl(e, base), q1 = __shfl(e, base+1), q2 = __shfl(e, base+2), q3 = __shfl(e, base+3);
      num0 += q0*bf2f(va.x); num1 += q1*bf2f(va.y); num2 += q2*bf2f(va.z); num3 += q3*bf2f(va.w);
    }
    float rd = 1.f/(den + 1e-16f);        // lane hh holds den for head hh
    float r0 = __shfl(rd, base), r1 = __shfl(rd, base+1), r2 = __shfl(rd, base+2), r3 = __shfl(rd, base+3);
    outv += num0*r0 + num1*r1 + num2*r2 + num3*r3;
  }
  int rA = type ? 1 : 0, rB = type ? 3 : 2;
  float bavg = 0.5f*(convBias[(layer*4 + rA)*64 + lane] + convBias[(layer*4 + rB)*64 + lane]);
  float z = fmaxf(outv*0.125f + bavg, 0.f);
  float* acc = ws + (type ? OAACC : OTACC);
  acc[(size_t)node*64 + lane] = z;
  // BN column stats -> 64 spread buckets (avoids same-line atomic serialization)
  __shared__ float sdm[2][256];
  sdm[0][t] = z; sdm[1][t] = z*z;
  __syncthreads();
  if (t < 64) {
    float s1 = sdm[0][t] + sdm[0][t+64] + sdm[0][t+128] + sdm[0][t+192];
    float s2 = sdm[1][t] + sdm[1][t+64] + sdm[1][t+128] + sdm[1][t+192];
    int bt = type ? 0 : 1;
    int bucket = blockIdx.x & 63;
    atomicAdd(&ws[BNSTB + bucket*256 + bt*128 + t], s1);
    atomicAdd(&ws[BNSTB + bucket*256 + bt*128 + 64 + t], s2);
  }
}

// ---------------- reduce 64 BN-stat buckets -> BNST ----------------
__global__ __launch_bounds__(256) void k_bnred(float* ws) {
  int t = threadIdx.x;
  float s = 0.f;
  #pragma unroll
  for (int b = 0; b < 64; ++b) s += ws[BNSTB + b*256 + t];
  ws[BNST + t] = s;
}

// ---------------- batchnorm + residual, writes xa/xt in place ----------------
__global__ __launch_bounds__(256) void k_bnnorm(const float* bnG, const float* bnB, float* ws, int layer) {
  int type = blockIdx.y;                  // 0 agent, 1 track
  int N = type ? NTr : NAg;
  float* acc = ws + (type ? OTACC : OAACC);
  float* x = ws + (type ? XT_OFF : XA_OFF);
  int i = blockIdx.x*256 + threadIdx.x;
  if (i >= N*64) return;
  int c = i & 63;
  float Nf = (float)N;
  float s1 = ws[BNST + type*128 + c], s2 = ws[BNST + type*128 + 64 + c];
  float mu = s1/Nf, var = s2/Nf - mu*mu;
  float g = bnG[(layer*2 + type)*64 + c], b = bnB[(layer*2 + type)*64 + c];
  float y = g*(acc[i]-mu)*rsqrtf(var + 1e-5f) + b;
  if (layer > 0) y += x[i];
  x[i] = y;
}

// ---------------- actor heads: wave per node, both heads in parallel ----------------
__global__ __launch_bounds__(256) void k_actor(const float* aW1, const float* ab1, const float* ag,
    const float* abe, const float* aW2, const float* ab2, const float* ws, float* out) {
  int type = blockIdx.y;
  int N = type ? NTr : NAg;
  int t = threadIdx.x, wv = t >> 6, lane = t & 63;
  int p = lane >> 5, j = lane & 31;   // head-pair member, hidden index
  int n = blockIdx.x*4 + wv;
  const float* xg = ws + (type ? XT_OFF : XA_OFF);
  __shared__ float xsh[4][64];
  {
    int nn = blockIdx.x*4 + (t >> 6);
    if (nn < N) xsh[t >> 6][t & 63] = xg[(size_t)nn*64 + (t & 63)];
  }
  __syncthreads();
  if (n >= N) return;
  int i = (type ? 2 : 0) + p;
  const float* W = aW1 + i*2048 + j;   // stride 32 per k
  float a0 = 0.f, a1 = 0.f, a2 = 0.f, a3 = 0.f;
  #pragma unroll
  for (int k = 0; k < 64; k += 4) {
    a0 += xsh[wv][k]   * W[k*32];
    a1 += xsh[wv][k+1] * W[(k+1)*32];
    a2 += xsh[wv][k+2] * W[(k+2)*32];
    a3 += xsh[wv][k+3] * W[(k+3)*32];
  }
  float tv = ((a0+a1)+(a2+a3)) + ab1[i*32 + j];
  float mu = wred32(tv) * (1.f/32.f);
  float dz = tv - mu;
  float var = wred32(dz*dz) * (1.f/32.f);
  float hn = fmaxf(ag[i*32+j]*dz*rsqrtf(var + 1e-5f) + abe[i*32+j], 0.f);
  float s = wred32(hn * aW2[i*32 + j]) + ab2[i];
  float val = softplusf(s) + 1.f;
  float vA = __shfl(val, 0);
  float vB = __shfl(val, 32);
  if (lane == 0) {
    int offA = type ? 24000 : 0, offB = type ? 54000 : 8000, offC = type ? 84000 : 16000;
    out[offA + n] = vA;
    out[offB + n] = vB;
    out[offC + n] = vA / (vA + vB);
  }
}

// ---------------- critic column stats ----------------
__global__ __launch_bounds__(256) void k_criticstats(float* ws) {
  int type = blockIdx.y;
  int N = type ? NTr : NAg;
  const float* x = ws + (type ? XT_OFF : XA_OFF);
  int t = threadIdx.x;
  int c = t & 63;
  float s1 = 0.f, s2 = 0.f, mx = -3.4e38f;
  for (int n = blockIdx.x*4 + (t>>6); n < N; n += gridDim.x*4) {
    float v = x[(size_t)n*64 + c];
    s1 += v; s2 += v*v; mx = fmaxf(mx, v);
  }
  __shared__ float sd[3][256];
  sd[0][t]=s1; sd[1][t]=s2; sd[2][t]=mx;
  __syncthreads();
  if (t < 64) {
    s1 = sd[0][t]+sd[0][t+64]+sd[0][t+128]+sd[0][t+192];
    s2 = sd[1][t]+sd[1][t+64]+sd[1][t+128]+sd[1][t+192];
    mx = fmaxf(fmaxf(sd[2][t],sd[2][t+64]), fmaxf(sd[2][t+128],sd[2][t+192]));
    atomicAdd(&ws[CST + type*192 + c], s1);
    atomicAdd(&ws[CST + type*192 + 64 + c], s2);
    atomicMax((unsigned*)&ws[CST + type*192 + 128 + c], fmap(mx));
  }
}

__device__ __forceinline__ float blocksum128(float v, float* red) {
  int t = threadIdx.x;
  red[t] = v; __syncthreads();
  #pragma unroll
  for (int s = 64; s > 0; s >>= 1) { if (t < s) red[t] += red[t+s]; __syncthreads(); }
  float r = red[0]; __syncthreads();
  return r;
}

// ---------------- critic MLP ----------------
__global__ __launch_bounds__(128) void k_critic(const float* cW1,const float* cb1,const float* cg1,const float* cbe1,
    const float* cW2,const float* cb2,const float* cg2,const float* cbe2,
    const float* cW3,const float* cb3,const float* cW4,const float* cb4,
    const float* ws, float* out) {
  __shared__ float g[384];
  __shared__ float h1[128];
  __shared__ float h2s[64];
  __shared__ float red[128];
  int t = threadIdx.x;
  if (t < 64) {
    #pragma unroll
    for (int type = 0; type < 2; ++type) {
      float Nf = type ? 30000.f : 8000.f;
      float s1 = ws[CST + type*192 + t];
      float s2 = ws[CST + type*192 + 64 + t];
      unsigned mu_ = __float_as_uint(ws[CST + type*192 + 128 + t]);
      float mean = s1 / Nf;
      float sd = sqrtf(fmaxf((s2 - Nf*mean*mean) / (Nf - 1.f), 0.f));
      g[type*192 + t] = mean;
      g[type*192 + 64 + t] = funmap(mu_);
      g[type*192 + 128 + t] = sd;
    }
  }
  __syncthreads();
  float v = cb1[t];
  for (int k = 0; k < 384; ++k) v += g[k] * cW1[k*128 + t];
  float mu = blocksum128(v, red) * (1.f/128.f);
  float d = v - mu;
  float var = blocksum128(d*d, red) * (1.f/128.f);
  h1[t] = fmaxf(cg1[t]*d*rsqrtf(var + 1e-5f) + cbe1[t], 0.f);
  __syncthreads();
  float v2 = 0.f;
  if (t < 64) { v2 = cb2[t]; for (int k = 0; k < 128; ++k) v2 += h1[k] * cW2[k*64 + t]; }
  float mu2 = blocksum128(t < 64 ? v2 : 0.f, red) * (1.f/64.f);
  float d2 = v2 - mu2;
  float var2 = blocksum128(t < 64 ? d2*d2 : 0.f, red) * (1.f/64.f);
  if (t < 64) h2s[t] = fmaxf(cg2[t]*d2*rsqrtf(var2 + 1e-5f) + cbe2[t], 0.f);
  __syncthreads();
  float v3 = 0.f;
  if (t < 32) {
    v3 = cb3[t];
    for (int k = 0; k < 64; ++k) v3 += h2s[k] * cW3[k*32 + t];
    v3 = fmaxf(v3, 0.f);
  }
  float s4 = blocksum128(t < 32 ? v3 * cW4[t] : 0.f, red);
  if (t == 0) out[114000] = s4 + cb4[0];
}

extern "C" void kernel_launch(void* const* d_in, const int* in_sizes, int n_in,
                              void* d_out, int out_size, void* d_ws, size_t ws_size,
                              hipStream_t stream) {
  const float* x_agent = (const float*)d_in[0];
  const float* x_track = (const float*)d_in[1];
  const int* s0 = (const int*)d_in[2]; const int* d0_ = (const int*)d_in[3];
  const int* s1 = (const int*)d_in[4]; const int* d1_ = (const int*)d_in[5];
  const int* s2 = (const int*)d_in[6]; const int* d2_ = (const int*)d_in[7];
  const int* s3 = (const int*)d_in[8]; const int* d3_ = (const int*)d_in[9];
  const float* aeW = (const float*)d_in[10]; const float* aeB = (const float*)d_in[11];
  const float* teW = (const float*)d_in[12]; const float* teB = (const float*)d_in[13];
  const float* convW    = (const float*)d_in[14];
  const float* convAsrc = (const float*)d_in[15];
  const float* convAdst = (const float*)d_in[16];
  const float* convBias = (const float*)d_in[17];
  const float* bnG = (const float*)d_in[18]; const float* bnB = (const float*)d_in[19];
  const float* aW1 = (const float*)d_in[20]; const float* ab1 = (const float*)d_in[21];
  const float* ag  = (const float*)d_in[22]; const float* abe = (const float*)d_in[23];
  const float* aW2 = (const float*)d_in[24]; const float* ab2 = (const float*)d_in[25];
  const float* cW1 = (const float*)d_in[26]; const float* cb1 = (const float*)d_in[27];
  const float* cg1 = (const float*)d_in[28]; const float* cbe1 = (const float*)d_in[29];
  const float* cW2 = (const float*)d_in[30]; const float* cb2 = (const float*)d_in[31];
  const float* cg2 = (const float*)d_in[32]; const float* cbe2 = (const float*)d_in[33];
  const float* cW3 = (const float*)d_in[34]; const float* cb3 = (const float*)d_in[35];
  const float* cW4 = (const float*)d_in[36]; const float* cb4 = (const float*)d_in[37];
  float* ws = (float*)d_ws;
  int* wsi = (int*)d_ws;
  float* out = (float*)d_out;

  hipMemsetAsync(wsi + ROWP_I, 0, (size_t)240128 * sizeof(int), stream);
  hipMemsetAsync(ws + CST, 0, (size_t)384 * sizeof(float), stream);

  k_encoder<<<dim3(7500, 2), 256, 0, stream>>>(x_agent, x_track, aeW, aeB, teW, teB, ws);

  k_hist<<<dim3(586, 4), 256, 0, stream>>>(d0_, d1_, d2_, d3_, wsi);
  k_scan<<<dim3(4), 256, 0, stream>>>(wsi);
  k_fill<<<dim3(586, 4), 256, 0, stream>>>(s0,d0_,s1,d1_,s2,d2_,s3,d3_, wsi);

  for (int l = 0; l < 3; ++l) {
    hipMemsetAsync(ws + BNSTB, 0, (size_t)16384 * sizeof(float), stream);
    k_ald<<<dim3(469, 4), 256, 0, stream>>>(convW, convAdst, ws, l);
    k_h_als<<<dim3(1875, 4), 256, 0, stream>>>(convW, convAsrc, ws, l);
    k_agg<<<dim3(7500, 2), 256, 0, stream>>>(convBias, ws, l);
    k_bnred<<<1, 256, 0, stream>>>(ws);
    k_bnnorm<<<dim3(7500, 2), 256, 0, stream>>>(bnG, bnB, ws, l);
  }

  k_criticstats<<<dim3(128, 2), 256, 0, stream>>>(ws);
  k_actor<<<dim3(7500, 2), 256, 0, stream>>>(aW1, ab1, ag, abe, aW2, ab2, ws, out);
  k_critic<<<1, 128, 0, stream>>>(cW1,cb1,cg1,cbe1,cW2,cb2,cg2,cbe2,cW3,cb3,cW4,cb4, ws, out);
}